// Round 11
// baseline (1000.609 us; speedup 1.0000x reference)
//
#include <hip/hip_runtime.h>
#include <hip/hip_bf16.h>

#define BB 16
#define SS 512
#define DD 1024
#define HH 16
#define LL 4
#define DHH 64
#define GK 1024

typedef __attribute__((ext_vector_type(8))) short short8;
typedef __attribute__((ext_vector_type(4))) float f32x4;

__device__ __forceinline__ unsigned short f2bf(float f) {
  union { float f; unsigned int u; } v; v.f = f;
  unsigned int r = v.u + 0x7FFFu + ((v.u >> 16) & 1u);
  return (unsigned short)(r >> 16);
}

__device__ __forceinline__ float wave_max(float v) {
#pragma unroll
  for (int off = 32; off > 0; off >>= 1) v = fmaxf(v, __shfl_xor(v, off));
  return v;
}
__device__ __forceinline__ float wave_sum(float v) {
#pragma unroll
  for (int off = 32; off > 0; off >>= 1) v += __shfl_xor(v, off);
  return v;
}
__device__ __forceinline__ float half_max(float v) {   // width-32 segment
#pragma unroll
  for (int off = 16; off > 0; off >>= 1) v = fmaxf(v, __shfl_xor(v, off));
  return v;
}
__device__ __forceinline__ float half_sum(float v) {
#pragma unroll
  for (int off = 16; off > 0; off >>= 1) v += __shfl_xor(v, off);
  return v;
}

// global -> LDS direct 16B copy. LDS dest is wave-uniform base + lane*16.
__device__ __forceinline__ void gl16(const void* g, void* l) {
  __builtin_amdgcn_global_load_lds(
      (const __attribute__((address_space(1))) unsigned int*)(uintptr_t)g,
      (__attribute__((address_space(3))) unsigned int*)(unsigned int)(uintptr_t)l,
      16, 0, 0);
}

// ---------------- weights fp32 -> bf16 ----------------
__global__ __launch_bounds__(256) void k_w2bf_qv(const float* __restrict__ wq,
                                                 const float* __restrict__ wv,
                                                 unsigned short* __restrict__ o) {
  size_t i4 = ((size_t)blockIdx.x * 256 + threadIdx.x) * 4;
  size_t l = i4 >> 21;
  size_t r = i4 & ((1u << 21) - 1);
  const float* src = (r < (1u << 20)) ? wq + (l << 20) + r
                                      : wv + (l << 20) + (r - (1u << 20));
  float4 v = *(const float4*)src;
  uint2 pk;
  pk.x = (unsigned)f2bf(v.x) | ((unsigned)f2bf(v.y) << 16);
  pk.y = (unsigned)f2bf(v.z) | ((unsigned)f2bf(v.w) << 16);
  *(uint2*)(o + i4) = pk;
}
__global__ __launch_bounds__(256) void k_w2bf(const float* __restrict__ w,
                                              unsigned short* __restrict__ o) {
  size_t i4 = ((size_t)blockIdx.x * 256 + threadIdx.x) * 4;
  float4 v = *(const float4*)(w + i4);
  uint2 pk;
  pk.x = (unsigned)f2bf(v.x) | ((unsigned)f2bf(v.y) << 16);
  pk.y = (unsigned)f2bf(v.z) | ((unsigned)f2bf(v.w) << 16);
  *(uint2*)(o + i4) = pk;
}

// ---------------- q0 = x + positional encoding (fp32 + bf16 shadow) ----------------
__global__ __launch_bounds__(256) void k_add_pe(const float* __restrict__ x,
                                                float* __restrict__ out,
                                                unsigned short* __restrict__ outb) {
  size_t i4 = ((size_t)blockIdx.x * 256 + threadIdx.x) * 4;
  int d0 = (int)(i4 & (DD - 1));
  int s = (int)((i4 >> 10) & (SS - 1));
  float4 xv = *(const float4*)(x + i4);
  int ip0 = d0 >> 1;
  float f0 = __expf((float)ip0 * -0.017988946039016f);
  float f1 = __expf((float)(ip0 + 1) * -0.017988946039016f);
  float s0v, c0v, s1v, c1v;
  __sincosf((float)s * f0, &s0v, &c0v);
  __sincosf((float)s * f1, &s1v, &c1v);
  float4 o;
  o.x = xv.x + s0v; o.y = xv.y + c0v; o.z = xv.z + s1v; o.w = xv.w + c1v;
  *(float4*)(out + i4) = o;
  uint2 pk;
  pk.x = (unsigned)f2bf(o.x) | ((unsigned)f2bf(o.y) << 16);
  pk.y = (unsigned)f2bf(o.z) | ((unsigned)f2bf(o.w) << 16);
  *(uint2*)(outb + i4) = pk;
}

// ---------------- C = A[M,K]bf16 @ W[N,K]^T bf16 + bias ----------------
// 128x128 tile, 4 waves, BK=32, gl16 staging, 2-phase double-buffered LDS.
// MODE 0: bf16 [M,1024]. MODE 2: fp32 [M,1024].
// MODE 3: fused QV (N=2048): col<1024 -> bf16 Qbf; col>=1024 -> transposed VtB.
template <int MODE>
__global__ __launch_bounds__(256) void k_gemm(
    const unsigned short* __restrict__ A, const unsigned short* __restrict__ W,
    const float* __restrict__ bias, const float* __restrict__ bias2,
    void* __restrict__ out, void* __restrict__ out2) {
  __shared__ unsigned short As[2][128 * 32];
  __shared__ unsigned short Bs[2][128 * 32];
  const int tid = threadIdx.x;
  const int lane = tid & 63;
  const int w = tid >> 6;
  const int wr = w >> 1, wc = w & 1;
  const int fr = lane & 15, fq = lane >> 4;

  int bid = blockIdx.x;
  const int cpx = gridDim.x >> 3;
  bid = (bid & 7) * cpx + (bid >> 3);
  const int bm = (bid & 63) * 128;
  const int bn = (bid >> 6) * 128;

  f32x4 acc[4][4] = {};

  const unsigned short* ga = A + (size_t)(bm + w * 16 + (lane >> 2)) * GK + (lane & 3) * 8;
  const unsigned short* gb = W + (size_t)(bn + w * 16 + (lane >> 2)) * GK + (lane & 3) * 8;

  auto STAGE = [&](int buf, int k0) {
    unsigned short* la = As[buf] + w * 512;
    unsigned short* lb = Bs[buf] + w * 512;
    gl16(ga + k0, la);
    gl16(ga + 64 * GK + k0, la + 2048);
    gl16(gb + k0, lb);
    gl16(gb + 64 * GK + k0, lb + 2048);
  };

  STAGE(0, 0);
  __syncthreads();
  int cur = 0;
  for (int k0 = 0; k0 < GK; k0 += 32) {
    if (k0 + 32 < GK) STAGE(cur ^ 1, k0 + 32);
    short8 af[4], bf[4];
#pragma unroll
    for (int m = 0; m < 4; ++m)
      af[m] = *(const short8*)(As[cur] + (wr * 64 + m * 16 + fr) * 32 + fq * 8);
#pragma unroll
    for (int n = 0; n < 4; ++n)
      bf[n] = *(const short8*)(Bs[cur] + (wc * 64 + n * 16 + fr) * 32 + fq * 8);
#pragma unroll
    for (int m = 0; m < 4; ++m)
#pragma unroll
      for (int n = 0; n < 4; ++n)
        acc[m][n] = __builtin_amdgcn_mfma_f32_16x16x32_bf16(af[m], bf[n], acc[m][n], 0, 0, 0);
    __syncthreads();
    cur ^= 1;
  }

#pragma unroll
  for (int m = 0; m < 4; ++m) {
    const int row0 = bm + wr * 64 + m * 16 + fq * 4;
#pragma unroll
    for (int n = 0; n < 4; ++n) {
      const int col = bn + wc * 64 + n * 16 + fr;
      if constexpr (MODE == 0) {
        const float bsv = bias[col];
        unsigned short* o = (unsigned short*)out;
#pragma unroll
        for (int r = 0; r < 4; ++r)
          o[(size_t)(row0 + r) * DD + col] = f2bf(acc[m][n][r] + bsv);
      } else if constexpr (MODE == 2) {
        const float bsv = bias[col];
        float* o = (float*)out;
#pragma unroll
        for (int r = 0; r < 4; ++r)
          o[(size_t)(row0 + r) * DD + col] = acc[m][n][r] + bsv;
      } else {  // MODE 3: fused QV
        if (col < DD) {
          const float bsv = bias[col];
          unsigned short* o = (unsigned short*)out;
#pragma unroll
          for (int r = 0; r < 4; ++r)
            o[(size_t)(row0 + r) * DD + col] = f2bf(acc[m][n][r] + bsv);
        } else {
          const int c2 = col - DD;
          const float bsv = bias2[c2];
          unsigned short* o = (unsigned short*)out2;
          const int bi = row0 >> 9, si = row0 & (SS - 1);
          uint2 pk;
          pk.x = (unsigned)f2bf(acc[m][n][0] + bsv) | ((unsigned)f2bf(acc[m][n][1] + bsv) << 16);
          pk.y = (unsigned)f2bf(acc[m][n][2] + bsv) | ((unsigned)f2bf(acc[m][n][3] + bsv) << 16);
          *(uint2*)(o + ((size_t)bi * DD + c2) * SS + si) = pk;
        }
      }
    }
  }
}

// ---------------- fused MFMA attention, BIG half (itiles 8..15) ----------------
// ALL MFMA operands loaded direct global->register (fragments are contiguous
// 16B chunks; K/V L2-resident across i-tile blocks). Only sc_s lives in LDS;
// barriers per block: 28 -> 2. Softmax identical to round 10.
__global__ __launch_bounds__(512) void k_attn_big(
    const unsigned short* __restrict__ Q, const unsigned short* __restrict__ Vt,
    const float* __restrict__ gam, unsigned short* __restrict__ AO,
    float* __restrict__ scores_out) {
  __shared__ float sc_s[32][516];          // 66048 B -> 2 blocks/CU

  const int tid = threadIdx.x;
  const int lane = tid & 63;
  const int w = tid >> 6;
  const int wr = w & 1;
  const int wc = w >> 1;
  const int fr = lane & 15, fq = lane >> 4;

  const int itile = 8 + (blockIdx.x & 7);
  const int bh = blockIdx.x >> 3;
  const int b = bh >> 4;
  const int h = bh & 15;
  const int i0 = itile * 32;
  const int njt = (itile + 2) >> 1;        // 5..8
  const int jcap = njt * 64;

  const unsigned short* Qb = Q + (size_t)b * SS * DD + h * DHH;
  const unsigned short* Vtb = Vt + ((size_t)b * DD + h * DHH) * SS;
  const float gneg = -fabsf(gam[h]);

  // A fragments (Q rows) — loop-invariant, direct global
  const unsigned short* qrow = Qb + (size_t)(i0 + wr * 16 + fr) * DD;
  short8 a0 = *(const short8*)(qrow + fq * 8);
  short8 a1 = *(const short8*)(qrow + 32 + fq * 8);

  // ---- QK^T: direct-global K fragments, one-tile prefetch, NO barriers ----
  const unsigned short* kf = Qb + (size_t)(wc * 16 + fr) * DD;
  short8 b0 = *(const short8*)(kf + fq * 8);
  short8 b1 = *(const short8*)(kf + 32 + fq * 8);
  for (int jt = 0; jt < njt; ++jt) {
    short8 nb0 = b0, nb1 = b1;
    if (jt + 1 < njt) {
      const unsigned short* nf = kf + (size_t)(jt + 1) * 64 * DD;
      nb0 = *(const short8*)(nf + fq * 8);
      nb1 = *(const short8*)(nf + 32 + fq * 8);
    }
    f32x4 s0 = {};
    s0 = __builtin_amdgcn_mfma_f32_16x16x32_bf16(a0, b0, s0, 0, 0, 0);
    s0 = __builtin_amdgcn_mfma_f32_16x16x32_bf16(a1, b1, s0, 0, 0, 0);

    const int j = jt * 64 + wc * 16 + fr;
#pragma unroll
    for (int r = 0; r < 4; ++r) {
      const int row = wr * 16 + fq * 4 + r;
      sc_s[row][j] = (j < i0 + row) ? s0[r] * 0.125f : -1e30f;
    }
    b0 = nb0; b1 = nb1;
  }
  __syncthreads();   // scores visible to all waves

  const int jb = lane << 3;
#pragma unroll 2
  for (int q = 0; q < 4; ++q) {
    const int r_i = w * 4 + q;
    const int gi = i0 + r_i;
    const float* rowp = &sc_s[r_i][0];
    float4 v0 = *(const float4*)(rowp + jb);
    float4 v1 = *(const float4*)(rowp + jb + 4);
    float sc[8] = {v0.x, v0.y, v0.z, v0.w, v1.x, v1.y, v1.z, v1.w};
#pragma unroll
    for (int c = 0; c < 8; ++c)
      if (jb + c >= jcap) sc[c] = -1e30f;

    // softmax#1: max-free (ratio-invariant)
    float p[8];
    float lsum = 0.0f;
#pragma unroll
    for (int c = 0; c < 8; ++c) {
      p[c] = __expf(sc[c]);              // masked -> 0
      lsum += p[c];
    }

    float xs = lsum;
#pragma unroll
    for (int off = 1; off < 64; off <<= 1) {
      float y = __shfl_up(xs, off);
      if (lane >= off) xs += y;
    }
    const float tot = __shfl(xs, 63);
    const float inv = 1.0f / tot;
    float run = xs - lsum;

    float s2[8];
#pragma unroll
    for (int c = 0; c < 8; ++c) {
      run += p[c];
      float cum = run * inv;
      float dist = sqrtf(fmaxf((1.0f - cum) * (float)(gi - (jb + c)), 0.0f));
      float te = __expf(gneg * dist);
      te = fminf(fmaxf(te, 1e-5f), 1e5f);
      s2[c] = sc[c] * te;
    }

    // softmax#2: max REQUIRED (maxout scale relies on max(e)==1)
    float m2 = s2[0];
#pragma unroll
    for (int c = 1; c < 8; ++c) m2 = fmaxf(m2, s2[c]);
    m2 = wave_max(m2);
    float e[8];
    float lsum2 = 0.0f;
#pragma unroll
    for (int c = 0; c < 8; ++c) {
      e[c] = __expf(s2[c] - m2);
      lsum2 += e[c];
    }
    float tot2 = wave_sum(lsum2);
    float mult = fminf(tot2, 5.0f) / tot2;

    float av[8];
#pragma unroll
    for (int c = 0; c < 8; ++c) {
      av[c] = (gi == 0) ? 0.0f : e[c] * mult;
    }

    if (scores_out) {
      float* so = scores_out + ((size_t)(b * HH + h) * SS + gi) * SS + jb;
      *(float4*)(so) = make_float4(av[0], av[1], av[2], av[3]);
      *(float4*)(so + 4) = make_float4(av[4], av[5], av[6], av[7]);
    }

    short8 pk;
#pragma unroll
    for (int c = 0; c < 8; ++c) pk[c] = (short)f2bf(av[c]);
    *(short8*)((unsigned short*)&sc_s[r_i][0] + jb) = pk;
  }
  __syncthreads();   // attn bf16 visible

  // ---- PV: direct-global V^T fragments, NO barriers ----
  const unsigned short* vf = Vtb + (size_t)(wc * 16 + fr) * SS;
  const unsigned short* arow = (const unsigned short*)&sc_s[wr * 16 + fr][0];
  short8 c0 = *(const short8*)(vf + fq * 8);
  short8 c1 = *(const short8*)(vf + 32 + fq * 8);
  f32x4 o0 = {};
  for (int jt = 0; jt < njt; ++jt) {
    short8 nc0 = c0, nc1 = c1;
    if (jt + 1 < njt) {
      const unsigned short* nf = vf + (jt + 1) * 64;
      nc0 = *(const short8*)(nf + fq * 8);
      nc1 = *(const short8*)(nf + 32 + fq * 8);
    }
    short8 pa0 = *(const short8*)(arow + jt * 64 + fq * 8);
    short8 pa1 = *(const short8*)(arow + jt * 64 + 32 + fq * 8);
    o0 = __builtin_amdgcn_mfma_f32_16x16x32_bf16(pa0, c0, o0, 0, 0, 0);
    o0 = __builtin_amdgcn_mfma_f32_16x16x32_bf16(pa1, c1, o0, 0, 0, 0);
    c0 = nc0; c1 = nc1;
  }

  {
    const int d = h * DHH + wc * 16 + fr;
#pragma unroll
    for (int r = 0; r < 4; ++r) {
      const int row = i0 + wr * 16 + fq * 4 + r;
      AO[((size_t)b * SS + row) * DD + d] = f2bf(o0[r]);
    }
  }
}

// ---------------- fused MFMA attention, SMALL half (itiles 0..7) ----------------
// Same direct-global fragment scheme; LDS = sc_s only (33 KB).
__global__ __launch_bounds__(512) void k_attn_small(
    const unsigned short* __restrict__ Q, const unsigned short* __restrict__ Vt,
    const float* __restrict__ gam, unsigned short* __restrict__ AO,
    float* __restrict__ scores_out) {
  __shared__ float sc_s[32][260];          // 33280 B

  const int tid = threadIdx.x;
  const int lane = tid & 63;
  const int w = tid >> 6;
  const int wr = w & 1;
  const int wc = w >> 1;
  const int fr = lane & 15, fq = lane >> 4;

  const int itile = blockIdx.x & 7;
  const int bh = blockIdx.x >> 3;
  const int b = bh >> 4;
  const int h = bh & 15;
  const int i0 = itile * 32;
  const int njt = (itile + 2) >> 1;        // 1..4
  const int jcap = njt * 64;

  const unsigned short* Qb = Q + (size_t)b * SS * DD + h * DHH;
  const unsigned short* Vtb = Vt + ((size_t)b * DD + h * DHH) * SS;
  const float gneg = -fabsf(gam[h]);

  const unsigned short* qrow = Qb + (size_t)(i0 + wr * 16 + fr) * DD;
  short8 a0 = *(const short8*)(qrow + fq * 8);
  short8 a1 = *(const short8*)(qrow + 32 + fq * 8);

  const unsigned short* kf = Qb + (size_t)(wc * 16 + fr) * DD;
  short8 b0 = *(const short8*)(kf + fq * 8);
  short8 b1 = *(const short8*)(kf + 32 + fq * 8);
  for (int jt = 0; jt < njt; ++jt) {
    short8 nb0 = b0, nb1 = b1;
    if (jt + 1 < njt) {
      const unsigned short* nf = kf + (size_t)(jt + 1) * 64 * DD;
      nb0 = *(const short8*)(nf + fq * 8);
      nb1 = *(const short8*)(nf + 32 + fq * 8);
    }
    f32x4 s0 = {};
    s0 = __builtin_amdgcn_mfma_f32_16x16x32_bf16(a0, b0, s0, 0, 0, 0);
    s0 = __builtin_amdgcn_mfma_f32_16x16x32_bf16(a1, b1, s0, 0, 0, 0);

    const int j = jt * 64 + wc * 16 + fr;
#pragma unroll
    for (int r = 0; r < 4; ++r) {
      const int row = wr * 16 + fq * 4 + r;
      sc_s[row][j] = (j < i0 + row) ? s0[r] * 0.125f : -1e30f;
    }
    b0 = nb0; b1 = nb1;
  }
  __syncthreads();

  const int half = lane >> 5;
  const int ll = lane & 31;
  const int jb = ll << 3;
  for (int q = 0; q < 2; ++q) {
    const int r_i = w * 4 + q * 2 + half;
    const int gi = i0 + r_i;
    const float* rowp = &sc_s[r_i][0];
    float4 v0 = *(const float4*)(rowp + jb);
    float4 v1 = *(const float4*)(rowp + jb + 4);
    float sc[8] = {v0.x, v0.y, v0.z, v0.w, v1.x, v1.y, v1.z, v1.w};
#pragma unroll
    for (int c = 0; c < 8; ++c)
      if (jb + c >= jcap) sc[c] = -1e30f;

    // softmax#1: max-free
    float p[8];
    float lsum = 0.0f;
#pragma unroll
    for (int c = 0; c < 8; ++c) {
      p[c] = __expf(sc[c]);
      lsum += p[c];
    }

    float xs = lsum;
#pragma unroll
    for (int off = 1; off < 32; off <<= 1) {
      float y = __shfl_up(xs, off, 32);
      if (ll >= off) xs += y;
    }
    const float tot = __shfl(xs, 31, 32);
    const float inv = 1.0f / tot;
    float run = xs - lsum;

    float s2[8];
#pragma unroll
    for (int c = 0; c < 8; ++c) {
      run += p[c];
      float cum = run * inv;
      float dist = sqrtf(fmaxf((1.0f - cum) * (float)(gi - (jb + c)), 0.0f));
      float te = __expf(gneg * dist);
      te = fminf(fmaxf(te, 1e-5f), 1e5f);
      s2[c] = sc[c] * te;
    }

    // softmax#2: max required for maxout
    float m2 = s2[0];
#pragma unroll
    for (int c = 1; c < 8; ++c) m2 = fmaxf(m2, s2[c]);
    m2 = half_max(m2);
    float e[8];
    float lsum2 = 0.0f;
#pragma unroll
    for (int c = 0; c < 8; ++c) {
      e[c] = __expf(s2[c] - m2);
      lsum2 += e[c];
    }
    const float tot2 = half_sum(lsum2);
    const float mult = fminf(tot2, 5.0f) / tot2;

    float av[8];
#pragma unroll
    for (int c = 0; c < 8; ++c) {
      av[c] = (gi == 0) ? 0.0f : e[c] * mult;
    }

    if (scores_out) {
      float* so = scores_out + ((size_t)(b * HH + h) * SS + gi) * SS + jb;
      *(float4*)(so) = make_float4(av[0], av[1], av[2], av[3]);
      *(float4*)(so + 4) = make_float4(av[4], av[5], av[6], av[7]);
      *(float4*)(so + 256) = make_float4(0.f, 0.f, 0.f, 0.f);
      *(float4*)(so + 260) = make_float4(0.f, 0.f, 0.f, 0.f);
    }

    short8 pk;
#pragma unroll
    for (int c = 0; c < 8; ++c) pk[c] = (short)f2bf(av[c]);
    *(short8*)((unsigned short*)&sc_s[r_i][0] + jb) = pk;
  }
  __syncthreads();

  const unsigned short* vf = Vtb + (size_t)(wc * 16 + fr) * SS;
  const unsigned short* arow = (const unsigned short*)&sc_s[wr * 16 + fr][0];
  short8 c0 = *(const short8*)(vf + fq * 8);
  short8 c1 = *(const short8*)(vf + 32 + fq * 8);
  f32x4 o0 = {};
  for (int jt = 0; jt < njt; ++jt) {
    short8 nc0 = c0, nc1 = c1;
    if (jt + 1 < njt) {
      const unsigned short* nf = vf + (jt + 1) * 64;
      nc0 = *(const short8*)(nf + fq * 8);
      nc1 = *(const short8*)(nf + 32 + fq * 8);
    }
    short8 pa0 = *(const short8*)(arow + jt * 64 + fq * 8);
    short8 pa1 = *(const short8*)(arow + jt * 64 + 32 + fq * 8);
    o0 = __builtin_amdgcn_mfma_f32_16x16x32_bf16(pa0, c0, o0, 0, 0, 0);
    o0 = __builtin_amdgcn_mfma_f32_16x16x32_bf16(pa1, c1, o0, 0, 0, 0);
    c0 = nc0; c1 = nc1;
  }

  {
    const int d = h * DHH + wc * 16 + fr;
#pragma unroll
    for (int r = 0; r < 4; ++r) {
      const int row = i0 + wr * 16 + fq * 4 + r;
      AO[((size_t)b * SS + row) * DD + d] = f2bf(o0[r]);
    }
  }
}

// ---------------- residual + layernorm (fp32 out, optional bf16 shadow) ----------------
__global__ __launch_bounds__(256) void k_res_ln(
    const float* __restrict__ x, const float* __restrict__ r,
    const float* __restrict__ w, const float* __restrict__ b,
    float* __restrict__ out, unsigned short* __restrict__ outb) {
  __shared__ float red[4];
  const int row = blockIdx.x;
  const int tid = threadIdx.x;
  const int lane = tid & 63, wv = tid >> 6;
  float4 y = ((const float4*)(x + (size_t)row * DD))[tid];
  if (r) {
    float4 rr = ((const float4*)(r + (size_t)row * DD))[tid];
    y.x += rr.x; y.y += rr.y; y.z += rr.z; y.w += rr.w;
  }
  float s = y.x + y.y + y.z + y.w;
  s = wave_sum(s);
  if (lane == 0) red[wv] = s;
  __syncthreads();
  float mean = (red[0] + red[1] + red[2] + red[3]) * (1.0f / DD);
  __syncthreads();
  float d0 = y.x - mean, d1 = y.y - mean, d2 = y.z - mean, d3 = y.w - mean;
  float s2 = d0 * d0 + d1 * d1 + d2 * d2 + d3 * d3;
  s2 = wave_sum(s2);
  if (lane == 0) red[wv] = s2;
  __syncthreads();
  float var = (red[0] + red[1] + red[2] + red[3]) * (1.0f / DD);
  float rstd = rsqrtf(var + 1e-5f);
  float4 ww = ((const float4*)w)[tid];
  float4 bb = ((const float4*)b)[tid];
  float4 o;
  o.x = d0 * rstd * ww.x + bb.x;
  o.y = d1 * rstd * ww.y + bb.y;
  o.z = d2 * rstd * ww.z + bb.z;
  o.w = d3 * rstd * ww.w + bb.w;
  ((float4*)(out + (size_t)row * DD))[tid] = o;
  if (outb) {
    uint2 pk;
    pk.x = (unsigned)f2bf(o.x) | ((unsigned)f2bf(o.y) << 16);
    pk.y = (unsigned)f2bf(o.z) | ((unsigned)f2bf(o.w) << 16);
    *(uint2*)(outb + (size_t)row * DD + tid * 4) = pk;
  }
}

extern "C" void kernel_launch(void* const* d_in, const int* in_sizes, int n_in,
                              void* d_out, int out_size, void* d_ws, size_t ws_size,
                              hipStream_t stream) {
  (void)in_sizes; (void)n_in; (void)out_size; (void)ws_size;
  const float* x = (const float*)d_in[0];
  const float* Wq = (const float*)d_in[2];
  const float* bq = (const float*)d_in[3];
  const float* Wv = (const float*)d_in[4];
  const float* bv = (const float*)d_in[5];
  const float* Wo = (const float*)d_in[6];
  const float* bo = (const float*)d_in[7];
  const float* gam = (const float*)d_in[8];
  const float* lnw = (const float*)d_in[9];
  const float* lnb = (const float*)d_in[10];
  const float* flnw = (const float*)d_in[11];
  const float* flnb = (const float*)d_in[12];

  float* out0 = (float*)d_out;
  float* scores = out0 + (size_t)BB * SS * DD;
  const size_t BUF = (size_t)BB * SS * DD;
  const size_t WSZ = (size_t)LL * DD * DD;
  const size_t BHSS = (size_t)BB * HH * SS * SS;

  float* P0 = (float*)d_ws;
  float* P1 = P0 + BUF;
  unsigned short* us = (unsigned short*)(P1 + BUF);
  unsigned short* Abf = us;
  unsigned short* Qbf = us + BUF;
  unsigned short* VtB = us + 2 * BUF;
  unsigned short* AObf = us + 3 * BUF;
  unsigned short* Wob = us + 4 * BUF;
  unsigned short* Wqvb = (unsigned short*)scores + (2 * BHSS - 2 * WSZ);

  const int M = BB * SS;

  k_w2bf_qv<<<dim3(2 * WSZ / 1024), 256, 0, stream>>>(Wq, Wv, Wqvb);
  k_w2bf<<<dim3(WSZ / 1024), 256, 0, stream>>>(Wo, Wob);
  k_add_pe<<<dim3(BUF / 1024), 256, 0, stream>>>(x, P0, Abf);

  float* Acur = P0;
  float* Pnx = P1;
  for (int l = 0; l < LL; ++l) {
    float* sc_dst = (l == LL - 1) ? scores : nullptr;
    k_gemm<3><<<dim3(1024), 256, 0, stream>>>(Abf, Wqvb + (size_t)l * 2048 * DD,
                                              bq + l * DD, bv + l * DD, Qbf, VtB);
    k_attn_small<<<dim3(BB * HH * 8), 512, 0, stream>>>(Qbf, VtB, gam + l * HH, AObf, sc_dst);
    k_attn_big<<<dim3(BB * HH * 8), 512, 0, stream>>>(Qbf, VtB, gam + l * HH, AObf, sc_dst);
    k_gemm<2><<<dim3(512), 256, 0, stream>>>(AObf, Wob + (size_t)l * DD * DD,
                                             bo + l * DD, nullptr, Pnx, nullptr);
    k_res_ln<<<dim3(M), 256, 0, stream>>>(Acur, Pnx, lnw + l * DD, lnb + l * DD, Pnx, Abf);
    float* t = Acur; Acur = Pnx; Pnx = t;
  }
  k_res_ln<<<dim3(M), 256, 0, stream>>>(Acur, nullptr, flnw, flnb, out0, nullptr);
}

// Round 12
// 905.552 us; speedup vs baseline: 1.1050x; 1.1050x over previous
//
#include <hip/hip_runtime.h>
#include <hip/hip_bf16.h>

#define BB 16
#define SS 512
#define DD 1024
#define HH 16
#define LL 4
#define DHH 64
#define GK 1024

typedef __attribute__((ext_vector_type(8))) short short8;
typedef __attribute__((ext_vector_type(4))) float f32x4;

__device__ __forceinline__ unsigned short f2bf(float f) {
  union { float f; unsigned int u; } v; v.f = f;
  unsigned int r = v.u + 0x7FFFu + ((v.u >> 16) & 1u);
  return (unsigned short)(r >> 16);
}

__device__ __forceinline__ float wave_max(float v) {
#pragma unroll
  for (int off = 32; off > 0; off >>= 1) v = fmaxf(v, __shfl_xor(v, off));
  return v;
}
__device__ __forceinline__ float wave_sum(float v) {
#pragma unroll
  for (int off = 32; off > 0; off >>= 1) v += __shfl_xor(v, off);
  return v;
}
__device__ __forceinline__ float half_max(float v) {   // width-32 segment
#pragma unroll
  for (int off = 16; off > 0; off >>= 1) v = fmaxf(v, __shfl_xor(v, off));
  return v;
}
__device__ __forceinline__ float half_sum(float v) {
#pragma unroll
  for (int off = 16; off > 0; off >>= 1) v += __shfl_xor(v, off);
  return v;
}

// global -> LDS direct 16B copy. LDS dest is wave-uniform base + lane*16.
__device__ __forceinline__ void gl16(const void* g, void* l) {
  __builtin_amdgcn_global_load_lds(
      (const __attribute__((address_space(1))) unsigned int*)(uintptr_t)g,
      (__attribute__((address_space(3))) unsigned int*)(unsigned int)(uintptr_t)l,
      16, 0, 0);
}

// ---------------- all weights fp32 -> bf16 in ONE launch ----------------
// dst oqv = [L][2048][1024] (rows 0-1023 Wq, 1024-2047 Wv); oo = Wo flat.
__global__ __launch_bounds__(256) void k_w2bf_all(
    const float* __restrict__ wq, const float* __restrict__ wv,
    const float* __restrict__ wo, unsigned short* __restrict__ oqv,
    unsigned short* __restrict__ oo) {
  size_t i4 = ((size_t)blockIdx.x * 256 + threadIdx.x) * 4;
  const size_t QV = (size_t)2 * LL * DD * DD;
  const float* src;
  unsigned short* dst;
  if (i4 < QV) {
    size_t l = i4 >> 21;
    size_t r = i4 & ((1u << 21) - 1);
    src = (r < (1u << 20)) ? wq + (l << 20) + r
                           : wv + (l << 20) + (r - (1u << 20));
    dst = oqv + i4;
  } else {
    size_t j = i4 - QV;
    src = wo + j;
    dst = oo + j;
  }
  float4 v = *(const float4*)src;
  uint2 pk;
  pk.x = (unsigned)f2bf(v.x) | ((unsigned)f2bf(v.y) << 16);
  pk.y = (unsigned)f2bf(v.z) | ((unsigned)f2bf(v.w) << 16);
  *(uint2*)dst = pk;
}

// ---------------- q0 = x + positional encoding (fp32 + bf16 shadow) ----------------
__global__ __launch_bounds__(256) void k_add_pe(const float* __restrict__ x,
                                                float* __restrict__ out,
                                                unsigned short* __restrict__ outb) {
  size_t i4 = ((size_t)blockIdx.x * 256 + threadIdx.x) * 4;
  int d0 = (int)(i4 & (DD - 1));
  int s = (int)((i4 >> 10) & (SS - 1));
  float4 xv = *(const float4*)(x + i4);
  int ip0 = d0 >> 1;
  float f0 = __expf((float)ip0 * -0.017988946039016f);
  float f1 = __expf((float)(ip0 + 1) * -0.017988946039016f);
  float s0v, c0v, s1v, c1v;
  __sincosf((float)s * f0, &s0v, &c0v);
  __sincosf((float)s * f1, &s1v, &c1v);
  float4 o;
  o.x = xv.x + s0v; o.y = xv.y + c0v; o.z = xv.z + s1v; o.w = xv.w + c1v;
  *(float4*)(out + i4) = o;
  uint2 pk;
  pk.x = (unsigned)f2bf(o.x) | ((unsigned)f2bf(o.y) << 16);
  pk.y = (unsigned)f2bf(o.z) | ((unsigned)f2bf(o.w) << 16);
  *(uint2*)(outb + i4) = pk;
}

// ---------------- C = A[M,K]bf16 @ W[N,K]^T bf16 + bias ----------------
// 128x128 tile, 4 waves, BK=32, gl16 staging, 2-phase double-buffered LDS.
// MODE 0: bf16 [M,1024]. MODE 2: fp32 [M,1024].
// MODE 3: fused QV (N=2048): col<1024 -> bf16 Qbf; col>=1024 -> transposed VtB.
template <int MODE>
__global__ __launch_bounds__(256) void k_gemm(
    const unsigned short* __restrict__ A, const unsigned short* __restrict__ W,
    const float* __restrict__ bias, const float* __restrict__ bias2,
    void* __restrict__ out, void* __restrict__ out2) {
  __shared__ unsigned short As[2][128 * 32];
  __shared__ unsigned short Bs[2][128 * 32];
  const int tid = threadIdx.x;
  const int lane = tid & 63;
  const int w = tid >> 6;
  const int wr = w >> 1, wc = w & 1;
  const int fr = lane & 15, fq = lane >> 4;

  int bid = blockIdx.x;
  const int cpx = gridDim.x >> 3;
  bid = (bid & 7) * cpx + (bid >> 3);
  const int bm = (bid & 63) * 128;
  const int bn = (bid >> 6) * 128;

  f32x4 acc[4][4] = {};

  const unsigned short* ga = A + (size_t)(bm + w * 16 + (lane >> 2)) * GK + (lane & 3) * 8;
  const unsigned short* gb = W + (size_t)(bn + w * 16 + (lane >> 2)) * GK + (lane & 3) * 8;

  auto STAGE = [&](int buf, int k0) {
    unsigned short* la = As[buf] + w * 512;
    unsigned short* lb = Bs[buf] + w * 512;
    gl16(ga + k0, la);
    gl16(ga + 64 * GK + k0, la + 2048);
    gl16(gb + k0, lb);
    gl16(gb + 64 * GK + k0, lb + 2048);
  };

  STAGE(0, 0);
  __syncthreads();
  int cur = 0;
  for (int k0 = 0; k0 < GK; k0 += 32) {
    if (k0 + 32 < GK) STAGE(cur ^ 1, k0 + 32);
    short8 af[4], bf[4];
#pragma unroll
    for (int m = 0; m < 4; ++m)
      af[m] = *(const short8*)(As[cur] + (wr * 64 + m * 16 + fr) * 32 + fq * 8);
#pragma unroll
    for (int n = 0; n < 4; ++n)
      bf[n] = *(const short8*)(Bs[cur] + (wc * 64 + n * 16 + fr) * 32 + fq * 8);
#pragma unroll
    for (int m = 0; m < 4; ++m)
#pragma unroll
      for (int n = 0; n < 4; ++n)
        acc[m][n] = __builtin_amdgcn_mfma_f32_16x16x32_bf16(af[m], bf[n], acc[m][n], 0, 0, 0);
    __syncthreads();
    cur ^= 1;
  }

#pragma unroll
  for (int m = 0; m < 4; ++m) {
    const int row0 = bm + wr * 64 + m * 16 + fq * 4;
#pragma unroll
    for (int n = 0; n < 4; ++n) {
      const int col = bn + wc * 64 + n * 16 + fr;
      if constexpr (MODE == 0) {
        const float bsv = bias[col];
        unsigned short* o = (unsigned short*)out;
#pragma unroll
        for (int r = 0; r < 4; ++r)
          o[(size_t)(row0 + r) * DD + col] = f2bf(acc[m][n][r] + bsv);
      } else if constexpr (MODE == 2) {
        const float bsv = bias[col];
        float* o = (float*)out;
#pragma unroll
        for (int r = 0; r < 4; ++r)
          o[(size_t)(row0 + r) * DD + col] = acc[m][n][r] + bsv;
      } else {  // MODE 3: fused QV
        if (col < DD) {
          const float bsv = bias[col];
          unsigned short* o = (unsigned short*)out;
#pragma unroll
          for (int r = 0; r < 4; ++r)
            o[(size_t)(row0 + r) * DD + col] = f2bf(acc[m][n][r] + bsv);
        } else {
          const int c2 = col - DD;
          const float bsv = bias2[c2];
          unsigned short* o = (unsigned short*)out2;
          const int bi = row0 >> 9, si = row0 & (SS - 1);
          uint2 pk;
          pk.x = (unsigned)f2bf(acc[m][n][0] + bsv) | ((unsigned)f2bf(acc[m][n][1] + bsv) << 16);
          pk.y = (unsigned)f2bf(acc[m][n][2] + bsv) | ((unsigned)f2bf(acc[m][n][3] + bsv) << 16);
          *(uint2*)(o + ((size_t)bi * DD + c2) * SS + si) = pk;
        }
      }
    }
  }
}

// ---------------- fused MFMA attention, BIG half (itiles 8..15) ----------------
// r10 staged structure; Q fragments in REGISTERS (loop-invariant, hoisted).
// K/V cooperatively staged in LDS with one-tile register prefetch.
__global__ __launch_bounds__(512) void k_attn_big(
    const unsigned short* __restrict__ Q, const unsigned short* __restrict__ Vt,
    const float* __restrict__ gam, unsigned short* __restrict__ AO,
    float* __restrict__ scores_out) {
  __shared__ float sc_s[32][516];          // 66048 B
  __shared__ unsigned short KV[64][72];    //  9216 B (K tile, then V^T tile)

  const int tid = threadIdx.x;
  const int lane = tid & 63;
  const int w = tid >> 6;
  const int wr = w & 1;
  const int wc = w >> 1;
  const int fr = lane & 15, fq = lane >> 4;

  const int itile = 8 + (blockIdx.x & 7);
  const int bh = blockIdx.x >> 3;
  const int b = bh >> 4;
  const int h = bh & 15;
  const int i0 = itile * 32;
  const int njt = (itile + 2) >> 1;        // 5..8
  const int jcap = njt * 64;

  const unsigned short* Qb = Q + (size_t)b * SS * DD + h * DHH;
  const unsigned short* Vtb = Vt + ((size_t)b * DD + h * DHH) * SS;
  const float gneg = -fabsf(gam[h]);

  const int srow = tid >> 3;
  const int sdb = (tid & 7) * 8;

  // Q fragments: loop-invariant, direct global -> registers
  const unsigned short* qrow = Qb + (size_t)(i0 + wr * 16 + fr) * DD;
  short8 a0 = *(const short8*)(qrow + fq * 8);
  short8 a1 = *(const short8*)(qrow + 32 + fq * 8);

  short8 kreg = *(const short8*)(Qb + (size_t)srow * DD + sdb);
  for (int jt = 0; jt < njt; ++jt) {
    *(short8*)&KV[srow][sdb] = kreg;
    const unsigned short* nsrc = (jt + 1 < njt)
        ? Qb + (size_t)((jt + 1) * 64 + srow) * DD + sdb
        : Vtb + (size_t)srow * SS + sdb;
    kreg = *(const short8*)nsrc;
    __syncthreads();

    short8 b0 = *(const short8*)&KV[wc * 16 + fr][fq * 8];
    short8 b1 = *(const short8*)&KV[wc * 16 + fr][32 + fq * 8];
    f32x4 s0 = {};
    s0 = __builtin_amdgcn_mfma_f32_16x16x32_bf16(a0, b0, s0, 0, 0, 0);
    s0 = __builtin_amdgcn_mfma_f32_16x16x32_bf16(a1, b1, s0, 0, 0, 0);

    const int j = jt * 64 + wc * 16 + fr;
#pragma unroll
    for (int r = 0; r < 4; ++r) {
      const int row = wr * 16 + fq * 4 + r;
      sc_s[row][j] = (j < i0 + row) ? s0[r] * 0.125f : -1e30f;
    }
    __syncthreads();
  }
  *(short8*)&KV[srow][sdb] = kreg;   // V tile 0

  const int jb = lane << 3;
#pragma unroll 2
  for (int q = 0; q < 4; ++q) {
    const int r_i = w * 4 + q;
    const int gi = i0 + r_i;
    const float* rowp = &sc_s[r_i][0];
    float4 v0 = *(const float4*)(rowp + jb);
    float4 v1 = *(const float4*)(rowp + jb + 4);
    float sc[8] = {v0.x, v0.y, v0.z, v0.w, v1.x, v1.y, v1.z, v1.w};
#pragma unroll
    for (int c = 0; c < 8; ++c)
      if (jb + c >= jcap) sc[c] = -1e30f;

    // softmax#1: max-free (ratio-invariant)
    float p[8];
    float lsum = 0.0f;
#pragma unroll
    for (int c = 0; c < 8; ++c) {
      p[c] = __expf(sc[c]);              // masked -> 0
      lsum += p[c];
    }

    float xs = lsum;
#pragma unroll
    for (int off = 1; off < 64; off <<= 1) {
      float y = __shfl_up(xs, off);
      if (lane >= off) xs += y;
    }
    const float tot = __shfl(xs, 63);    // scan lane63 == row total
    const float inv = 1.0f / tot;
    float run = xs - lsum;

    float s2[8];
#pragma unroll
    for (int c = 0; c < 8; ++c) {
      run += p[c];
      float cum = run * inv;
      float dist = sqrtf(fmaxf((1.0f - cum) * (float)(gi - (jb + c)), 0.0f));
      float te = __expf(gneg * dist);
      te = fminf(fmaxf(te, 1e-5f), 1e5f);
      s2[c] = sc[c] * te;
    }

    // softmax#2: max REQUIRED (maxout scale relies on max(e)==1)
    float m2 = s2[0];
#pragma unroll
    for (int c = 1; c < 8; ++c) m2 = fmaxf(m2, s2[c]);
    m2 = wave_max(m2);
    float e[8];
    float lsum2 = 0.0f;
#pragma unroll
    for (int c = 0; c < 8; ++c) {
      e[c] = __expf(s2[c] - m2);
      lsum2 += e[c];
    }
    float tot2 = wave_sum(lsum2);
    float mult = fminf(tot2, 5.0f) / tot2;

    float av[8];
#pragma unroll
    for (int c = 0; c < 8; ++c) {
      av[c] = (gi == 0) ? 0.0f : e[c] * mult;
    }

    if (scores_out) {
      float* so = scores_out + ((size_t)(b * HH + h) * SS + gi) * SS + jb;
      *(float4*)(so) = make_float4(av[0], av[1], av[2], av[3]);
      *(float4*)(so + 4) = make_float4(av[4], av[5], av[6], av[7]);
    }

    short8 pk;
#pragma unroll
    for (int c = 0; c < 8; ++c) pk[c] = (short)f2bf(av[c]);
    *(short8*)((unsigned short*)&sc_s[r_i][0] + jb) = pk;
  }
  __syncthreads();   // attn bf16 + V0 visible

  short8 vreg;
  if (njt > 1) vreg = *(const short8*)(Vtb + (size_t)srow * SS + 64 + sdb);
  f32x4 o0 = {};
  for (int jt = 0; jt < njt; ++jt) {
    const unsigned short* arow = (const unsigned short*)&sc_s[wr * 16 + fr][0];
    short8 pa0 = *(const short8*)(arow + jt * 64 + fq * 8);
    short8 pa1 = *(const short8*)(arow + jt * 64 + 32 + fq * 8);
    short8 c0 = *(const short8*)&KV[wc * 16 + fr][fq * 8];
    short8 c1 = *(const short8*)&KV[wc * 16 + fr][32 + fq * 8];
    o0 = __builtin_amdgcn_mfma_f32_16x16x32_bf16(pa0, c0, o0, 0, 0, 0);
    o0 = __builtin_amdgcn_mfma_f32_16x16x32_bf16(pa1, c1, o0, 0, 0, 0);
    __syncthreads();                       // KV reads done
    if (jt + 1 < njt) {
      *(short8*)&KV[srow][sdb] = vreg;
      if (jt + 2 < njt) vreg = *(const short8*)(Vtb + (size_t)srow * SS + (jt + 2) * 64 + sdb);
      __syncthreads();                     // next V tile visible
    }
  }

  {
    const int d = h * DHH + wc * 16 + fr;
#pragma unroll
    for (int r = 0; r < 4; ++r) {
      const int row = i0 + wr * 16 + fq * 4 + r;
      AO[((size_t)b * SS + row) * DD + d] = f2bf(o0[r]);
    }
  }
}

// ---------------- fused MFMA attention, SMALL half (itiles 0..7) ----------------
// Two rows per softmax pass (width-32 segments); Q frags in registers.
__global__ __launch_bounds__(512) void k_attn_small(
    const unsigned short* __restrict__ Q, const unsigned short* __restrict__ Vt,
    const float* __restrict__ gam, unsigned short* __restrict__ AO,
    float* __restrict__ scores_out) {
  __shared__ float sc_s[32][260];          // 33280 B
  __shared__ unsigned short KV[64][72];    //  9216 B => 42496 B total

  const int tid = threadIdx.x;
  const int lane = tid & 63;
  const int w = tid >> 6;
  const int wr = w & 1;
  const int wc = w >> 1;
  const int fr = lane & 15, fq = lane >> 4;

  const int itile = blockIdx.x & 7;        // 0..7
  const int bh = blockIdx.x >> 3;
  const int b = bh >> 4;
  const int h = bh & 15;
  const int i0 = itile * 32;
  const int njt = (itile + 2) >> 1;        // 1..4
  const int jcap = njt * 64;

  const unsigned short* Qb = Q + (size_t)b * SS * DD + h * DHH;
  const unsigned short* Vtb = Vt + ((size_t)b * DD + h * DHH) * SS;
  const float gneg = -fabsf(gam[h]);

  const int srow = tid >> 3;
  const int sdb = (tid & 7) * 8;

  const unsigned short* qrow = Qb + (size_t)(i0 + wr * 16 + fr) * DD;
  short8 a0 = *(const short8*)(qrow + fq * 8);
  short8 a1 = *(const short8*)(qrow + 32 + fq * 8);

  short8 kreg = *(const short8*)(Qb + (size_t)srow * DD + sdb);
  for (int jt = 0; jt < njt; ++jt) {
    *(short8*)&KV[srow][sdb] = kreg;
    const unsigned short* nsrc = (jt + 1 < njt)
        ? Qb + (size_t)((jt + 1) * 64 + srow) * DD + sdb
        : Vtb + (size_t)srow * SS + sdb;
    kreg = *(const short8*)nsrc;
    __syncthreads();

    short8 b0 = *(const short8*)&KV[wc * 16 + fr][fq * 8];
    short8 b1 = *(const short8*)&KV[wc * 16 + fr][32 + fq * 8];
    f32x4 s0 = {};
    s0 = __builtin_amdgcn_mfma_f32_16x16x32_bf16(a0, b0, s0, 0, 0, 0);
    s0 = __builtin_amdgcn_mfma_f32_16x16x32_bf16(a1, b1, s0, 0, 0, 0);

    const int j = jt * 64 + wc * 16 + fr;
#pragma unroll
    for (int r = 0; r < 4; ++r) {
      const int row = wr * 16 + fq * 4 + r;
      sc_s[row][j] = (j < i0 + row) ? s0[r] * 0.125f : -1e30f;
    }
    __syncthreads();
  }
  *(short8*)&KV[srow][sdb] = kreg;   // V tile 0

  const int half = lane >> 5;
  const int ll = lane & 31;
  const int jb = ll << 3;
  for (int q = 0; q < 2; ++q) {
    const int r_i = w * 4 + q * 2 + half;
    const int gi = i0 + r_i;
    const float* rowp = &sc_s[r_i][0];
    float4 v0 = *(const float4*)(rowp + jb);
    float4 v1 = *(const float4*)(rowp + jb + 4);
    float sc[8] = {v0.x, v0.y, v0.z, v0.w, v1.x, v1.y, v1.z, v1.w};
#pragma unroll
    for (int c = 0; c < 8; ++c)
      if (jb + c >= jcap) sc[c] = -1e30f;

    // softmax#1: max-free
    float p[8];
    float lsum = 0.0f;
#pragma unroll
    for (int c = 0; c < 8; ++c) {
      p[c] = __expf(sc[c]);
      lsum += p[c];
    }

    float xs = lsum;
#pragma unroll
    for (int off = 1; off < 32; off <<= 1) {
      float y = __shfl_up(xs, off, 32);
      if (ll >= off) xs += y;
    }
    const float tot = __shfl(xs, 31, 32);
    const float inv = 1.0f / tot;
    float run = xs - lsum;

    float s2[8];
#pragma unroll
    for (int c = 0; c < 8; ++c) {
      run += p[c];
      float cum = run * inv;
      float dist = sqrtf(fmaxf((1.0f - cum) * (float)(gi - (jb + c)), 0.0f));
      float te = __expf(gneg * dist);
      te = fminf(fmaxf(te, 1e-5f), 1e5f);
      s2[c] = sc[c] * te;
    }

    // softmax#2: max required for maxout
    float m2 = s2[0];
#pragma unroll
    for (int c = 1; c < 8; ++c) m2 = fmaxf(m2, s2[c]);
    m2 = half_max(m2);
    float e[8];
    float lsum2 = 0.0f;
#pragma unroll
    for (int c = 0; c < 8; ++c) {
      e[c] = __expf(s2[c] - m2);
      lsum2 += e[c];
    }
    const float tot2 = half_sum(lsum2);
    const float mult = fminf(tot2, 5.0f) / tot2;

    float av[8];
#pragma unroll
    for (int c = 0; c < 8; ++c) {
      av[c] = (gi == 0) ? 0.0f : e[c] * mult;
    }

    if (scores_out) {
      float* so = scores_out + ((size_t)(b * HH + h) * SS + gi) * SS + jb;
      *(float4*)(so) = make_float4(av[0], av[1], av[2], av[3]);
      *(float4*)(so + 4) = make_float4(av[4], av[5], av[6], av[7]);
      *(float4*)(so + 256) = make_float4(0.f, 0.f, 0.f, 0.f);
      *(float4*)(so + 260) = make_float4(0.f, 0.f, 0.f, 0.f);
    }

    short8 pk;
#pragma unroll
    for (int c = 0; c < 8; ++c) pk[c] = (short)f2bf(av[c]);
    *(short8*)((unsigned short*)&sc_s[r_i][0] + jb) = pk;
  }
  __syncthreads();

  short8 vreg;
  if (njt > 1) vreg = *(const short8*)(Vtb + (size_t)srow * SS + 64 + sdb);
  f32x4 o0 = {};
  for (int jt = 0; jt < njt; ++jt) {
    const unsigned short* arow = (const unsigned short*)&sc_s[wr * 16 + fr][0];
    short8 pa0 = *(const short8*)(arow + jt * 64 + fq * 8);
    short8 pa1 = *(const short8*)(arow + jt * 64 + 32 + fq * 8);
    short8 c0 = *(const short8*)&KV[wc * 16 + fr][fq * 8];
    short8 c1 = *(const short8*)&KV[wc * 16 + fr][32 + fq * 8];
    o0 = __builtin_amdgcn_mfma_f32_16x16x32_bf16(pa0, c0, o0, 0, 0, 0);
    o0 = __builtin_amdgcn_mfma_f32_16x16x32_bf16(pa1, c1, o0, 0, 0, 0);
    __syncthreads();
    if (jt + 1 < njt) {
      *(short8*)&KV[srow][sdb] = vreg;
      if (jt + 2 < njt) vreg = *(const short8*)(Vtb + (size_t)srow * SS + (jt + 2) * 64 + sdb);
      __syncthreads();
    }
  }

  {
    const int d = h * DHH + wc * 16 + fr;
#pragma unroll
    for (int r = 0; r < 4; ++r) {
      const int row = i0 + wr * 16 + fq * 4 + r;
      AO[((size_t)b * SS + row) * DD + d] = f2bf(o0[r]);
    }
  }
}

// ---------------- residual + layernorm (fp32 out, optional bf16 shadow) ----------------
__global__ __launch_bounds__(256) void k_res_ln(
    const float* __restrict__ x, const float* __restrict__ r,
    const float* __restrict__ w, const float* __restrict__ b,
    float* __restrict__ out, unsigned short* __restrict__ outb) {
  __shared__ float red[4];
  const int row = blockIdx.x;
  const int tid = threadIdx.x;
  const int lane = tid & 63, wv = tid >> 6;
  float4 y = ((const float4*)(x + (size_t)row * DD))[tid];
  if (r) {
    float4 rr = ((const float4*)(r + (size_t)row * DD))[tid];
    y.x += rr.x; y.y += rr.y; y.z += rr.z; y.w += rr.w;
  }
  float s = y.x + y.y + y.z + y.w;
  s = wave_sum(s);
  if (lane == 0) red[wv] = s;
  __syncthreads();
  float mean = (red[0] + red[1] + red[2] + red[3]) * (1.0f / DD);
  __syncthreads();
  float d0 = y.x - mean, d1 = y.y - mean, d2 = y.z - mean, d3 = y.w - mean;
  float s2 = d0 * d0 + d1 * d1 + d2 * d2 + d3 * d3;
  s2 = wave_sum(s2);
  if (lane == 0) red[wv] = s2;
  __syncthreads();
  float var = (red[0] + red[1] + red[2] + red[3]) * (1.0f / DD);
  float rstd = rsqrtf(var + 1e-5f);
  float4 ww = ((const float4*)w)[tid];
  float4 bb = ((const float4*)b)[tid];
  float4 o;
  o.x = d0 * rstd * ww.x + bb.x;
  o.y = d1 * rstd * ww.y + bb.y;
  o.z = d2 * rstd * ww.z + bb.z;
  o.w = d3 * rstd * ww.w + bb.w;
  ((float4*)(out + (size_t)row * DD))[tid] = o;
  if (outb) {
    uint2 pk;
    pk.x = (unsigned)f2bf(o.x) | ((unsigned)f2bf(o.y) << 16);
    pk.y = (unsigned)f2bf(o.z) | ((unsigned)f2bf(o.w) << 16);
    *(uint2*)(outb + (size_t)row * DD + tid * 4) = pk;
  }
}

extern "C" void kernel_launch(void* const* d_in, const int* in_sizes, int n_in,
                              void* d_out, int out_size, void* d_ws, size_t ws_size,
                              hipStream_t stream) {
  (void)in_sizes; (void)n_in; (void)out_size; (void)ws_size;
  const float* x = (const float*)d_in[0];
  const float* Wq = (const float*)d_in[2];
  const float* bq = (const float*)d_in[3];
  const float* Wv = (const float*)d_in[4];
  const float* bv = (const float*)d_in[5];
  const float* Wo = (const float*)d_in[6];
  const float* bo = (const float*)d_in[7];
  const float* gam = (const float*)d_in[8];
  const float* lnw = (const float*)d_in[9];
  const float* lnb = (const float*)d_in[10];
  const float* flnw = (const float*)d_in[11];
  const float* flnb = (const float*)d_in[12];

  float* out0 = (float*)d_out;
  float* scores = out0 + (size_t)BB * SS * DD;
  const size_t BUF = (size_t)BB * SS * DD;
  const size_t WSZ = (size_t)LL * DD * DD;
  const size_t BHSS = (size_t)BB * HH * SS * SS;

  float* P0 = (float*)d_ws;
  float* P1 = P0 + BUF;
  unsigned short* us = (unsigned short*)(P1 + BUF);
  unsigned short* Abf = us;
  unsigned short* Qbf = us + BUF;
  unsigned short* VtB = us + 2 * BUF;
  unsigned short* AObf = us + 3 * BUF;
  unsigned short* Wob = us + 4 * BUF;
  unsigned short* Wqvb = (unsigned short*)scores + (2 * BHSS - 2 * WSZ);

  const int M = BB * SS;

  k_w2bf_all<<<dim3(3 * WSZ / 1024), 256, 0, stream>>>(Wq, Wv, Wo, Wqvb, Wob);
  k_add_pe<<<dim3(BUF / 1024), 256, 0, stream>>>(x, P0, Abf);

  float* Acur = P0;
  float* Pnx = P1;
  for (int l = 0; l < LL; ++l) {
    float* sc_dst = (l == LL - 1) ? scores : nullptr;
    k_gemm<3><<<dim3(1024), 256, 0, stream>>>(Abf, Wqvb + (size_t)l * 2048 * DD,
                                              bq + l * DD, bv + l * DD, Qbf, VtB);
    k_attn_small<<<dim3(BB * HH * 8), 512, 0, stream>>>(Qbf, VtB, gam + l * HH, AObf, sc_dst);
    k_attn_big<<<dim3(BB * HH * 8), 512, 0, stream>>>(Qbf, VtB, gam + l * HH, AObf, sc_dst);
    k_gemm<2><<<dim3(512), 256, 0, stream>>>(AObf, Wob + (size_t)l * DD * DD,
                                             bo + l * DD, nullptr, Pnx, nullptr);
    k_res_ln<<<dim3(M), 256, 0, stream>>>(Acur, Pnx, lnw + l * DD, lnb + l * DD, Pnx, Abf);
    float* t = Acur; Acur = Pnx; Pnx = t;
  }
  k_res_ln<<<dim3(M), 256, 0, stream>>>(Acur, nullptr, flnw, flnb, out0, nullptr);
}

// Round 13
// 863.415 us; speedup vs baseline: 1.1589x; 1.0488x over previous
//
#include <hip/hip_runtime.h>
#include <hip/hip_bf16.h>

#define BB 16
#define SS 512
#define DD 1024
#define HH 16
#define LL 4
#define DHH 64
#define GK 1024

typedef __attribute__((ext_vector_type(8))) short short8;
typedef __attribute__((ext_vector_type(4))) float f32x4;

__device__ __forceinline__ unsigned short f2bf(float f) {
  union { float f; unsigned int u; } v; v.f = f;
  unsigned int r = v.u + 0x7FFFu + ((v.u >> 16) & 1u);
  return (unsigned short)(r >> 16);
}

__device__ __forceinline__ float wave_max(float v) {
#pragma unroll
  for (int off = 32; off > 0; off >>= 1) v = fmaxf(v, __shfl_xor(v, off));
  return v;
}
__device__ __forceinline__ float wave_sum(float v) {
#pragma unroll
  for (int off = 32; off > 0; off >>= 1) v += __shfl_xor(v, off);
  return v;
}
__device__ __forceinline__ float half_max(float v) {   // width-32 segment
#pragma unroll
  for (int off = 16; off > 0; off >>= 1) v = fmaxf(v, __shfl_xor(v, off));
  return v;
}
__device__ __forceinline__ float half_sum(float v) {
#pragma unroll
  for (int off = 16; off > 0; off >>= 1) v += __shfl_xor(v, off);
  return v;
}

// global -> LDS direct 16B copy. LDS dest is wave-uniform base + lane*16.
__device__ __forceinline__ void gl16(const void* g, void* l) {
  __builtin_amdgcn_global_load_lds(
      (const __attribute__((address_space(1))) unsigned int*)(uintptr_t)g,
      (__attribute__((address_space(3))) unsigned int*)(unsigned int)(uintptr_t)l,
      16, 0, 0);
}

// ---------------- all weights fp32 -> bf16 in ONE launch ----------------
// dst oqv = [L][2048][1024] (rows 0-1023 Wq, 1024-2047 Wv); oo = Wo flat.
__global__ __launch_bounds__(256) void k_w2bf_all(
    const float* __restrict__ wq, const float* __restrict__ wv,
    const float* __restrict__ wo, unsigned short* __restrict__ oqv,
    unsigned short* __restrict__ oo) {
  size_t i4 = ((size_t)blockIdx.x * 256 + threadIdx.x) * 4;
  const size_t QV = (size_t)2 * LL * DD * DD;
  const float* src;
  unsigned short* dst;
  if (i4 < QV) {
    size_t l = i4 >> 21;
    size_t r = i4 & ((1u << 21) - 1);
    src = (r < (1u << 20)) ? wq + (l << 20) + r
                           : wv + (l << 20) + (r - (1u << 20));
    dst = oqv + i4;
  } else {
    size_t j = i4 - QV;
    src = wo + j;
    dst = oo + j;
  }
  float4 v = *(const float4*)src;
  uint2 pk;
  pk.x = (unsigned)f2bf(v.x) | ((unsigned)f2bf(v.y) << 16);
  pk.y = (unsigned)f2bf(v.z) | ((unsigned)f2bf(v.w) << 16);
  *(uint2*)dst = pk;
}

// ---------------- q0 = x + positional encoding (fp32 + bf16 shadow) ----------------
__global__ __launch_bounds__(256) void k_add_pe(const float* __restrict__ x,
                                                float* __restrict__ out,
                                                unsigned short* __restrict__ outb) {
  size_t i4 = ((size_t)blockIdx.x * 256 + threadIdx.x) * 4;
  int d0 = (int)(i4 & (DD - 1));
  int s = (int)((i4 >> 10) & (SS - 1));
  float4 xv = *(const float4*)(x + i4);
  int ip0 = d0 >> 1;
  float f0 = __expf((float)ip0 * -0.017988946039016f);
  float f1 = __expf((float)(ip0 + 1) * -0.017988946039016f);
  float s0v, c0v, s1v, c1v;
  __sincosf((float)s * f0, &s0v, &c0v);
  __sincosf((float)s * f1, &s1v, &c1v);
  float4 o;
  o.x = xv.x + s0v; o.y = xv.y + c0v; o.z = xv.z + s1v; o.w = xv.w + c1v;
  *(float4*)(out + i4) = o;
  uint2 pk;
  pk.x = (unsigned)f2bf(o.x) | ((unsigned)f2bf(o.y) << 16);
  pk.y = (unsigned)f2bf(o.z) | ((unsigned)f2bf(o.w) << 16);
  *(uint2*)(outb + i4) = pk;
}

// ---------------- C = A[M,K]bf16 @ W[N,K]^T bf16 + bias ----------------
// 128x128 tile, 4 waves, BK=32, gl16 staging, 2-phase double-buffered LDS.
// MODE 0: bf16 [M,1024]. MODE 2: fp32 [M,1024].
// MODE 3: fused QV (N=2048): col<1024 -> bf16 Qbf; col>=1024 -> transposed VtB.
template <int MODE>
__global__ __launch_bounds__(256) void k_gemm(
    const unsigned short* __restrict__ A, const unsigned short* __restrict__ W,
    const float* __restrict__ bias, const float* __restrict__ bias2,
    void* __restrict__ out, void* __restrict__ out2) {
  __shared__ unsigned short As[2][128 * 32];
  __shared__ unsigned short Bs[2][128 * 32];
  const int tid = threadIdx.x;
  const int lane = tid & 63;
  const int w = tid >> 6;
  const int wr = w >> 1, wc = w & 1;
  const int fr = lane & 15, fq = lane >> 4;

  int bid = blockIdx.x;
  const int cpx = gridDim.x >> 3;
  bid = (bid & 7) * cpx + (bid >> 3);
  const int bm = (bid & 63) * 128;
  const int bn = (bid >> 6) * 128;

  f32x4 acc[4][4] = {};

  const unsigned short* ga = A + (size_t)(bm + w * 16 + (lane >> 2)) * GK + (lane & 3) * 8;
  const unsigned short* gb = W + (size_t)(bn + w * 16 + (lane >> 2)) * GK + (lane & 3) * 8;

  auto STAGE = [&](int buf, int k0) {
    unsigned short* la = As[buf] + w * 512;
    unsigned short* lb = Bs[buf] + w * 512;
    gl16(ga + k0, la);
    gl16(ga + 64 * GK + k0, la + 2048);
    gl16(gb + k0, lb);
    gl16(gb + 64 * GK + k0, lb + 2048);
  };

  STAGE(0, 0);
  __syncthreads();
  int cur = 0;
  for (int k0 = 0; k0 < GK; k0 += 32) {
    if (k0 + 32 < GK) STAGE(cur ^ 1, k0 + 32);
    short8 af[4], bf[4];
#pragma unroll
    for (int m = 0; m < 4; ++m)
      af[m] = *(const short8*)(As[cur] + (wr * 64 + m * 16 + fr) * 32 + fq * 8);
#pragma unroll
    for (int n = 0; n < 4; ++n)
      bf[n] = *(const short8*)(Bs[cur] + (wc * 64 + n * 16 + fr) * 32 + fq * 8);
#pragma unroll
    for (int m = 0; m < 4; ++m)
#pragma unroll
      for (int n = 0; n < 4; ++n)
        acc[m][n] = __builtin_amdgcn_mfma_f32_16x16x32_bf16(af[m], bf[n], acc[m][n], 0, 0, 0);
    __syncthreads();
    cur ^= 1;
  }

#pragma unroll
  for (int m = 0; m < 4; ++m) {
    const int row0 = bm + wr * 64 + m * 16 + fq * 4;
#pragma unroll
    for (int n = 0; n < 4; ++n) {
      const int col = bn + wc * 64 + n * 16 + fr;
      if constexpr (MODE == 0) {
        const float bsv = bias[col];
        unsigned short* o = (unsigned short*)out;
#pragma unroll
        for (int r = 0; r < 4; ++r)
          o[(size_t)(row0 + r) * DD + col] = f2bf(acc[m][n][r] + bsv);
      } else if constexpr (MODE == 2) {
        const float bsv = bias[col];
        float* o = (float*)out;
#pragma unroll
        for (int r = 0; r < 4; ++r)
          o[(size_t)(row0 + r) * DD + col] = acc[m][n][r] + bsv;
      } else {  // MODE 3: fused QV
        if (col < DD) {
          const float bsv = bias[col];
          unsigned short* o = (unsigned short*)out;
#pragma unroll
          for (int r = 0; r < 4; ++r)
            o[(size_t)(row0 + r) * DD + col] = f2bf(acc[m][n][r] + bsv);
        } else {
          const int c2 = col - DD;
          const float bsv = bias2[c2];
          unsigned short* o = (unsigned short*)out2;
          const int bi = row0 >> 9, si = row0 & (SS - 1);
          uint2 pk;
          pk.x = (unsigned)f2bf(acc[m][n][0] + bsv) | ((unsigned)f2bf(acc[m][n][1] + bsv) << 16);
          pk.y = (unsigned)f2bf(acc[m][n][2] + bsv) | ((unsigned)f2bf(acc[m][n][3] + bsv) << 16);
          *(uint2*)(o + ((size_t)bi * DD + c2) * SS + si) = pk;
        }
      }
    }
  }
}

// ---------------- fused MFMA attention, MERGED (all 16 itiles) ----------------
// One launch per layer: 4096 blocks, longest itiles dispatched FIRST
// (itile = 15 - t) for LPT packing; short blocks backfill the tail.
// itile>=8: full-wave 4-pass softmax; itile<8: half-wave 2-pass softmax.
// Arithmetic identical to round 12's two kernels.
__global__ __launch_bounds__(512) void k_attn(
    const unsigned short* __restrict__ Q, const unsigned short* __restrict__ Vt,
    const float* __restrict__ gam, unsigned short* __restrict__ AO,
    float* __restrict__ scores_out) {
  __shared__ float sc_s[32][516];          // 66048 B
  __shared__ unsigned short KV[64][72];    //  9216 B (K tile, then V^T tile)

  const int tid = threadIdx.x;
  const int lane = tid & 63;
  const int w = tid >> 6;
  const int wr = w & 1;
  const int wc = w >> 1;
  const int fr = lane & 15, fq = lane >> 4;

  const int itile = 15 - (blockIdx.x >> 8);   // 15..0: longest first
  const int bh = blockIdx.x & 255;
  const int b = bh >> 4;
  const int h = bh & 15;
  const int i0 = itile * 32;
  const int njt = (itile + 2) >> 1;           // 1..8
  const int jcap = njt * 64;

  const unsigned short* Qb = Q + (size_t)b * SS * DD + h * DHH;
  const unsigned short* Vtb = Vt + ((size_t)b * DD + h * DHH) * SS;
  const float gneg = -fabsf(gam[h]);

  const int srow = tid >> 3;
  const int sdb = (tid & 7) * 8;

  // Q fragments: loop-invariant, direct global -> registers
  const unsigned short* qrow = Qb + (size_t)(i0 + wr * 16 + fr) * DD;
  short8 a0 = *(const short8*)(qrow + fq * 8);
  short8 a1 = *(const short8*)(qrow + 32 + fq * 8);

  short8 kreg = *(const short8*)(Qb + (size_t)srow * DD + sdb);
  for (int jt = 0; jt < njt; ++jt) {
    *(short8*)&KV[srow][sdb] = kreg;
    const unsigned short* nsrc = (jt + 1 < njt)
        ? Qb + (size_t)((jt + 1) * 64 + srow) * DD + sdb
        : Vtb + (size_t)srow * SS + sdb;
    kreg = *(const short8*)nsrc;
    __syncthreads();

    short8 b0 = *(const short8*)&KV[wc * 16 + fr][fq * 8];
    short8 b1 = *(const short8*)&KV[wc * 16 + fr][32 + fq * 8];
    f32x4 s0 = {};
    s0 = __builtin_amdgcn_mfma_f32_16x16x32_bf16(a0, b0, s0, 0, 0, 0);
    s0 = __builtin_amdgcn_mfma_f32_16x16x32_bf16(a1, b1, s0, 0, 0, 0);

    const int j = jt * 64 + wc * 16 + fr;
#pragma unroll
    for (int r = 0; r < 4; ++r) {
      const int row = wr * 16 + fq * 4 + r;
      sc_s[row][j] = (j < i0 + row) ? s0[r] * 0.125f : -1e30f;
    }
    __syncthreads();
  }
  *(short8*)&KV[srow][sdb] = kreg;   // V tile 0

  if (itile >= 8) {
    // ---- full-wave softmax, 4 passes ----
    const int jb = lane << 3;
#pragma unroll 2
    for (int q = 0; q < 4; ++q) {
      const int r_i = w * 4 + q;
      const int gi = i0 + r_i;
      const float* rowp = &sc_s[r_i][0];
      float4 v0 = *(const float4*)(rowp + jb);
      float4 v1 = *(const float4*)(rowp + jb + 4);
      float sc[8] = {v0.x, v0.y, v0.z, v0.w, v1.x, v1.y, v1.z, v1.w};
#pragma unroll
      for (int c = 0; c < 8; ++c)
        if (jb + c >= jcap) sc[c] = -1e30f;

      // softmax#1: max-free (ratio-invariant)
      float p[8];
      float lsum = 0.0f;
#pragma unroll
      for (int c = 0; c < 8; ++c) {
        p[c] = __expf(sc[c]);
        lsum += p[c];
      }

      float xs = lsum;
#pragma unroll
      for (int off = 1; off < 64; off <<= 1) {
        float y = __shfl_up(xs, off);
        if (lane >= off) xs += y;
      }
      const float tot = __shfl(xs, 63);
      const float inv = 1.0f / tot;
      float run = xs - lsum;

      float s2[8];
#pragma unroll
      for (int c = 0; c < 8; ++c) {
        run += p[c];
        float cum = run * inv;
        float dist = sqrtf(fmaxf((1.0f - cum) * (float)(gi - (jb + c)), 0.0f));
        float te = __expf(gneg * dist);
        te = fminf(fmaxf(te, 1e-5f), 1e5f);
        s2[c] = sc[c] * te;
      }

      // softmax#2: max REQUIRED (maxout scale relies on max(e)==1)
      float m2 = s2[0];
#pragma unroll
      for (int c = 1; c < 8; ++c) m2 = fmaxf(m2, s2[c]);
      m2 = wave_max(m2);
      float e[8];
      float lsum2 = 0.0f;
#pragma unroll
      for (int c = 0; c < 8; ++c) {
        e[c] = __expf(s2[c] - m2);
        lsum2 += e[c];
      }
      float tot2 = wave_sum(lsum2);
      float mult = fminf(tot2, 5.0f) / tot2;

      float av[8];
#pragma unroll
      for (int c = 0; c < 8; ++c) av[c] = (gi == 0) ? 0.0f : e[c] * mult;

      if (scores_out) {
        float* so = scores_out + ((size_t)(b * HH + h) * SS + gi) * SS + jb;
        *(float4*)(so) = make_float4(av[0], av[1], av[2], av[3]);
        *(float4*)(so + 4) = make_float4(av[4], av[5], av[6], av[7]);
      }

      short8 pk;
#pragma unroll
      for (int c = 0; c < 8; ++c) pk[c] = (short)f2bf(av[c]);
      *(short8*)((unsigned short*)&sc_s[r_i][0] + jb) = pk;
    }
  } else {
    // ---- half-wave softmax, 2 passes (jcap <= 256) ----
    const int half = lane >> 5;
    const int ll = lane & 31;
    const int jb = ll << 3;
    for (int q = 0; q < 2; ++q) {
      const int r_i = w * 4 + q * 2 + half;
      const int gi = i0 + r_i;
      const float* rowp = &sc_s[r_i][0];
      float4 v0 = *(const float4*)(rowp + jb);
      float4 v1 = *(const float4*)(rowp + jb + 4);
      float sc[8] = {v0.x, v0.y, v0.z, v0.w, v1.x, v1.y, v1.z, v1.w};
#pragma unroll
      for (int c = 0; c < 8; ++c)
        if (jb + c >= jcap) sc[c] = -1e30f;

      // softmax#1: max-free
      float p[8];
      float lsum = 0.0f;
#pragma unroll
      for (int c = 0; c < 8; ++c) {
        p[c] = __expf(sc[c]);
        lsum += p[c];
      }

      float xs = lsum;
#pragma unroll
      for (int off = 1; off < 32; off <<= 1) {
        float y = __shfl_up(xs, off, 32);
        if (ll >= off) xs += y;
      }
      const float tot = __shfl(xs, 31, 32);
      const float inv = 1.0f / tot;
      float run = xs - lsum;

      float s2[8];
#pragma unroll
      for (int c = 0; c < 8; ++c) {
        run += p[c];
        float cum = run * inv;
        float dist = sqrtf(fmaxf((1.0f - cum) * (float)(gi - (jb + c)), 0.0f));
        float te = __expf(gneg * dist);
        te = fminf(fmaxf(te, 1e-5f), 1e5f);
        s2[c] = sc[c] * te;
      }

      // softmax#2: max required for maxout
      float m2 = s2[0];
#pragma unroll
      for (int c = 1; c < 8; ++c) m2 = fmaxf(m2, s2[c]);
      m2 = half_max(m2);
      float e[8];
      float lsum2 = 0.0f;
#pragma unroll
      for (int c = 0; c < 8; ++c) {
        e[c] = __expf(s2[c] - m2);
        lsum2 += e[c];
      }
      const float tot2 = half_sum(lsum2);
      const float mult = fminf(tot2, 5.0f) / tot2;

      float av[8];
#pragma unroll
      for (int c = 0; c < 8; ++c) av[c] = (gi == 0) ? 0.0f : e[c] * mult;

      if (scores_out) {
        float* so = scores_out + ((size_t)(b * HH + h) * SS + gi) * SS + jb;
        *(float4*)(so) = make_float4(av[0], av[1], av[2], av[3]);
        *(float4*)(so + 4) = make_float4(av[4], av[5], av[6], av[7]);
        *(float4*)(so + 256) = make_float4(0.f, 0.f, 0.f, 0.f);
        *(float4*)(so + 260) = make_float4(0.f, 0.f, 0.f, 0.f);
      }

      short8 pk;
#pragma unroll
      for (int c = 0; c < 8; ++c) pk[c] = (short)f2bf(av[c]);
      *(short8*)((unsigned short*)&sc_s[r_i][0] + jb) = pk;
    }
  }
  __syncthreads();   // attn bf16 + V0 visible

  short8 vreg;
  if (njt > 1) vreg = *(const short8*)(Vtb + (size_t)srow * SS + 64 + sdb);
  f32x4 o0 = {};
  for (int jt = 0; jt < njt; ++jt) {
    const unsigned short* arow = (const unsigned short*)&sc_s[wr * 16 + fr][0];
    short8 pa0 = *(const short8*)(arow + jt * 64 + fq * 8);
    short8 pa1 = *(const short8*)(arow + jt * 64 + 32 + fq * 8);
    short8 c0 = *(const short8*)&KV[wc * 16 + fr][fq * 8];
    short8 c1 = *(const short8*)&KV[wc * 16 + fr][32 + fq * 8];
    o0 = __builtin_amdgcn_mfma_f32_16x16x32_bf16(pa0, c0, o0, 0, 0, 0);
    o0 = __builtin_amdgcn_mfma_f32_16x16x32_bf16(pa1, c1, o0, 0, 0, 0);
    __syncthreads();                       // KV reads done
    if (jt + 1 < njt) {
      *(short8*)&KV[srow][sdb] = vreg;
      if (jt + 2 < njt) vreg = *(const short8*)(Vtb + (size_t)srow * SS + (jt + 2) * 64 + sdb);
      __syncthreads();                     // next V tile visible
    }
  }

  {
    const int d = h * DHH + wc * 16 + fr;
#pragma unroll
    for (int r = 0; r < 4; ++r) {
      const int row = i0 + wr * 16 + fq * 4 + r;
      AO[((size_t)b * SS + row) * DD + d] = f2bf(o0[r]);
    }
  }
}

// ---------------- residual + layernorm (fp32 out, optional bf16 shadow) ----------------
__global__ __launch_bounds__(256) void k_res_ln(
    const float* __restrict__ x, const float* __restrict__ r,
    const float* __restrict__ w, const float* __restrict__ b,
    float* __restrict__ out, unsigned short* __restrict__ outb) {
  __shared__ float red[4];
  const int row = blockIdx.x;
  const int tid = threadIdx.x;
  const int lane = tid & 63, wv = tid >> 6;
  float4 y = ((const float4*)(x + (size_t)row * DD))[tid];
  if (r) {
    float4 rr = ((const float4*)(r + (size_t)row * DD))[tid];
    y.x += rr.x; y.y += rr.y; y.z += rr.z; y.w += rr.w;
  }
  float s = y.x + y.y + y.z + y.w;
  s = wave_sum(s);
  if (lane == 0) red[wv] = s;
  __syncthreads();
  float mean = (red[0] + red[1] + red[2] + red[3]) * (1.0f / DD);
  __syncthreads();
  float d0 = y.x - mean, d1 = y.y - mean, d2 = y.z - mean, d3 = y.w - mean;
  float s2 = d0 * d0 + d1 * d1 + d2 * d2 + d3 * d3;
  s2 = wave_sum(s2);
  if (lane == 0) red[wv] = s2;
  __syncthreads();
  float var = (red[0] + red[1] + red[2] + red[3]) * (1.0f / DD);
  float rstd = rsqrtf(var + 1e-5f);
  float4 ww = ((const float4*)w)[tid];
  float4 bb = ((const float4*)b)[tid];
  float4 o;
  o.x = d0 * rstd * ww.x + bb.x;
  o.y = d1 * rstd * ww.y + bb.y;
  o.z = d2 * rstd * ww.z + bb.z;
  o.w = d3 * rstd * ww.w + bb.w;
  ((float4*)(out + (size_t)row * DD))[tid] = o;
  if (outb) {
    uint2 pk;
    pk.x = (unsigned)f2bf(o.x) | ((unsigned)f2bf(o.y) << 16);
    pk.y = (unsigned)f2bf(o.z) | ((unsigned)f2bf(o.w) << 16);
    *(uint2*)(outb + (size_t)row * DD + tid * 4) = pk;
  }
}

extern "C" void kernel_launch(void* const* d_in, const int* in_sizes, int n_in,
                              void* d_out, int out_size, void* d_ws, size_t ws_size,
                              hipStream_t stream) {
  (void)in_sizes; (void)n_in; (void)out_size; (void)ws_size;
  const float* x = (const float*)d_in[0];
  const float* Wq = (const float*)d_in[2];
  const float* bq = (const float*)d_in[3];
  const float* Wv = (const float*)d_in[4];
  const float* bv = (const float*)d_in[5];
  const float* Wo = (const float*)d_in[6];
  const float* bo = (const float*)d_in[7];
  const float* gam = (const float*)d_in[8];
  const float* lnw = (const float*)d_in[9];
  const float* lnb = (const float*)d_in[10];
  const float* flnw = (const float*)d_in[11];
  const float* flnb = (const float*)d_in[12];

  float* out0 = (float*)d_out;
  float* scores = out0 + (size_t)BB * SS * DD;
  const size_t BUF = (size_t)BB * SS * DD;
  const size_t WSZ = (size_t)LL * DD * DD;
  const size_t BHSS = (size_t)BB * HH * SS * SS;

  float* P0 = (float*)d_ws;
  float* P1 = P0 + BUF;
  unsigned short* us = (unsigned short*)(P1 + BUF);
  unsigned short* Abf = us;
  unsigned short* Qbf = us + BUF;
  unsigned short* VtB = us + 2 * BUF;
  unsigned short* AObf = us + 3 * BUF;
  unsigned short* Wob = us + 4 * BUF;
  unsigned short* Wqvb = (unsigned short*)scores + (2 * BHSS - 2 * WSZ);

  const int M = BB * SS;

  k_w2bf_all<<<dim3(3 * WSZ / 1024), 256, 0, stream>>>(Wq, Wv, Wo, Wqvb, Wob);
  k_add_pe<<<dim3(BUF / 1024), 256, 0, stream>>>(x, P0, Abf);

  float* Acur = P0;
  float* Pnx = P1;
  for (int l = 0; l < LL; ++l) {
    float* sc_dst = (l == LL - 1) ? scores : nullptr;
    k_gemm<3><<<dim3(1024), 256, 0, stream>>>(Abf, Wqvb + (size_t)l * 2048 * DD,
                                              bq + l * DD, bv + l * DD, Qbf, VtB);
    k_attn<<<dim3(BB * HH * 16), 512, 0, stream>>>(Qbf, VtB, gam + l * HH, AObf, sc_dst);
    k_gemm<2><<<dim3(512), 256, 0, stream>>>(AObf, Wob + (size_t)l * DD * DD,
                                             bo + l * DD, nullptr, Pnx, nullptr);
    k_res_ln<<<dim3(M), 256, 0, stream>>>(Acur, Pnx, lnw + l * DD, lnb + l * DD, Pnx, Abf);
    float* t = Acur; Acur = Pnx; Pnx = t;
  }
  k_res_ln<<<dim3(M), 256, 0, stream>>>(Acur, nullptr, flnw, flnb, out0, nullptr);
}

// Round 14
// 820.814 us; speedup vs baseline: 1.2190x; 1.0519x over previous
//
#include <hip/hip_runtime.h>
#include <hip/hip_bf16.h>

#define BB 16
#define SS 512
#define DD 1024
#define HH 16
#define LL 4
#define DHH 64
#define GK 1024

typedef __attribute__((ext_vector_type(8))) short short8;
typedef __attribute__((ext_vector_type(4))) float f32x4;

__device__ __forceinline__ unsigned short f2bf(float f) {
  union { float f; unsigned int u; } v; v.f = f;
  unsigned int r = v.u + 0x7FFFu + ((v.u >> 16) & 1u);
  return (unsigned short)(r >> 16);
}
__device__ __forceinline__ float bf2f(unsigned short u) {
  union { unsigned int i; float f; } v; v.i = ((unsigned)u) << 16; return v.f;
}

__device__ __forceinline__ float wave_max(float v) {
#pragma unroll
  for (int off = 32; off > 0; off >>= 1) v = fmaxf(v, __shfl_xor(v, off));
  return v;
}
__device__ __forceinline__ float wave_sum(float v) {
#pragma unroll
  for (int off = 32; off > 0; off >>= 1) v += __shfl_xor(v, off);
  return v;
}
__device__ __forceinline__ float half_max(float v) {   // width-32 segment
#pragma unroll
  for (int off = 16; off > 0; off >>= 1) v = fmaxf(v, __shfl_xor(v, off));
  return v;
}
__device__ __forceinline__ float half_sum(float v) {
#pragma unroll
  for (int off = 16; off > 0; off >>= 1) v += __shfl_xor(v, off);
  return v;
}

// global -> LDS direct 16B copy. LDS dest is wave-uniform base + lane*16.
__device__ __forceinline__ void gl16(const void* g, void* l) {
  __builtin_amdgcn_global_load_lds(
      (const __attribute__((address_space(1))) unsigned int*)(uintptr_t)g,
      (__attribute__((address_space(3))) unsigned int*)(unsigned int)(uintptr_t)l,
      16, 0, 0);
}

// ---------------- all weights fp32 -> bf16 in ONE launch ----------------
// dst oqv = [L][2048][1024] (rows 0-1023 Wq, 1024-2047 Wv); oo = Wo flat.
__global__ __launch_bounds__(256) void k_w2bf_all(
    const float* __restrict__ wq, const float* __restrict__ wv,
    const float* __restrict__ wo, unsigned short* __restrict__ oqv,
    unsigned short* __restrict__ oo) {
  size_t i4 = ((size_t)blockIdx.x * 256 + threadIdx.x) * 4;
  const size_t QV = (size_t)2 * LL * DD * DD;
  const float* src;
  unsigned short* dst;
  if (i4 < QV) {
    size_t l = i4 >> 21;
    size_t r = i4 & ((1u << 21) - 1);
    src = (r < (1u << 20)) ? wq + (l << 20) + r
                           : wv + (l << 20) + (r - (1u << 20));
    dst = oqv + i4;
  } else {
    size_t j = i4 - QV;
    src = wo + j;
    dst = oo + j;
  }
  float4 v = *(const float4*)src;
  uint2 pk;
  pk.x = (unsigned)f2bf(v.x) | ((unsigned)f2bf(v.y) << 16);
  pk.y = (unsigned)f2bf(v.z) | ((unsigned)f2bf(v.w) << 16);
  *(uint2*)dst = pk;
}

// ---------------- q0 = bf16(x + positional encoding) ----------------
__global__ __launch_bounds__(256) void k_add_pe(const float* __restrict__ x,
                                                unsigned short* __restrict__ outb) {
  size_t i4 = ((size_t)blockIdx.x * 256 + threadIdx.x) * 4;
  int d0 = (int)(i4 & (DD - 1));
  int s = (int)((i4 >> 10) & (SS - 1));
  float4 xv = *(const float4*)(x + i4);
  int ip0 = d0 >> 1;
  float f0 = __expf((float)ip0 * -0.017988946039016f);
  float f1 = __expf((float)(ip0 + 1) * -0.017988946039016f);
  float s0v, c0v, s1v, c1v;
  __sincosf((float)s * f0, &s0v, &c0v);
  __sincosf((float)s * f1, &s1v, &c1v);
  float o0 = xv.x + s0v, o1 = xv.y + c0v, o2 = xv.z + s1v, o3 = xv.w + c1v;
  uint2 pk;
  pk.x = (unsigned)f2bf(o0) | ((unsigned)f2bf(o1) << 16);
  pk.y = (unsigned)f2bf(o2) | ((unsigned)f2bf(o3) << 16);
  *(uint2*)(outb + i4) = pk;
}

// ---------------- C = A[M,K]bf16 @ W[N,K]^T bf16 + bias ----------------
// 128x128 tile, 4 waves, BK=32, gl16 staging, 2-phase double-buffered LDS.
// MODE 0: bf16 [M,1024].
// MODE 3: fused QV (N=2048): col<1024 -> bf16 Qbf; col>=1024 -> transposed VtB.
template <int MODE>
__global__ __launch_bounds__(256) void k_gemm(
    const unsigned short* __restrict__ A, const unsigned short* __restrict__ W,
    const float* __restrict__ bias, const float* __restrict__ bias2,
    void* __restrict__ out, void* __restrict__ out2) {
  __shared__ unsigned short As[2][128 * 32];
  __shared__ unsigned short Bs[2][128 * 32];
  const int tid = threadIdx.x;
  const int lane = tid & 63;
  const int w = tid >> 6;
  const int wr = w >> 1, wc = w & 1;
  const int fr = lane & 15, fq = lane >> 4;

  int bid = blockIdx.x;
  const int cpx = gridDim.x >> 3;
  bid = (bid & 7) * cpx + (bid >> 3);
  const int bm = (bid & 63) * 128;
  const int bn = (bid >> 6) * 128;

  f32x4 acc[4][4] = {};

  const unsigned short* ga = A + (size_t)(bm + w * 16 + (lane >> 2)) * GK + (lane & 3) * 8;
  const unsigned short* gb = W + (size_t)(bn + w * 16 + (lane >> 2)) * GK + (lane & 3) * 8;

  auto STAGE = [&](int buf, int k0) {
    unsigned short* la = As[buf] + w * 512;
    unsigned short* lb = Bs[buf] + w * 512;
    gl16(ga + k0, la);
    gl16(ga + 64 * GK + k0, la + 2048);
    gl16(gb + k0, lb);
    gl16(gb + 64 * GK + k0, lb + 2048);
  };

  STAGE(0, 0);
  __syncthreads();
  int cur = 0;
  for (int k0 = 0; k0 < GK; k0 += 32) {
    if (k0 + 32 < GK) STAGE(cur ^ 1, k0 + 32);
    short8 af[4], bf[4];
#pragma unroll
    for (int m = 0; m < 4; ++m)
      af[m] = *(const short8*)(As[cur] + (wr * 64 + m * 16 + fr) * 32 + fq * 8);
#pragma unroll
    for (int n = 0; n < 4; ++n)
      bf[n] = *(const short8*)(Bs[cur] + (wc * 64 + n * 16 + fr) * 32 + fq * 8);
#pragma unroll
    for (int m = 0; m < 4; ++m)
#pragma unroll
      for (int n = 0; n < 4; ++n)
        acc[m][n] = __builtin_amdgcn_mfma_f32_16x16x32_bf16(af[m], bf[n], acc[m][n], 0, 0, 0);
    __syncthreads();
    cur ^= 1;
  }

#pragma unroll
  for (int m = 0; m < 4; ++m) {
    const int row0 = bm + wr * 64 + m * 16 + fq * 4;
#pragma unroll
    for (int n = 0; n < 4; ++n) {
      const int col = bn + wc * 64 + n * 16 + fr;
      if constexpr (MODE == 0) {
        const float bsv = bias[col];
        unsigned short* o = (unsigned short*)out;
#pragma unroll
        for (int r = 0; r < 4; ++r)
          o[(size_t)(row0 + r) * DD + col] = f2bf(acc[m][n][r] + bsv);
      } else {  // MODE 3: fused QV
        if (col < DD) {
          const float bsv = bias[col];
          unsigned short* o = (unsigned short*)out;
#pragma unroll
          for (int r = 0; r < 4; ++r)
            o[(size_t)(row0 + r) * DD + col] = f2bf(acc[m][n][r] + bsv);
        } else {
          const int c2 = col - DD;
          const float bsv = bias2[c2];
          unsigned short* o = (unsigned short*)out2;
          const int bi = row0 >> 9, si = row0 & (SS - 1);
          uint2 pk;
          pk.x = (unsigned)f2bf(acc[m][n][0] + bsv) | ((unsigned)f2bf(acc[m][n][1] + bsv) << 16);
          pk.y = (unsigned)f2bf(acc[m][n][2] + bsv) | ((unsigned)f2bf(acc[m][n][3] + bsv) << 16);
          *(uint2*)(o + ((size_t)bi * DD + c2) * SS + si) = pk;
        }
      }
    }
  }
}

// ---------------- fused MFMA attention, MERGED (all 16 itiles) ----------------
// 4096 blocks, longest itiles first (LPT). setprio(1) around MFMA pairs (T5).
__global__ __launch_bounds__(512) void k_attn(
    const unsigned short* __restrict__ Q, const unsigned short* __restrict__ Vt,
    const float* __restrict__ gam, unsigned short* __restrict__ AO,
    float* __restrict__ scores_out) {
  __shared__ float sc_s[32][516];          // 66048 B
  __shared__ unsigned short KV[64][72];    //  9216 B (K tile, then V^T tile)

  const int tid = threadIdx.x;
  const int lane = tid & 63;
  const int w = tid >> 6;
  const int wr = w & 1;
  const int wc = w >> 1;
  const int fr = lane & 15, fq = lane >> 4;

  const int itile = 15 - (blockIdx.x >> 8);   // 15..0: longest first
  const int bh = blockIdx.x & 255;
  const int b = bh >> 4;
  const int h = bh & 15;
  const int i0 = itile * 32;
  const int njt = (itile + 2) >> 1;           // 1..8
  const int jcap = njt * 64;

  const unsigned short* Qb = Q + (size_t)b * SS * DD + h * DHH;
  const unsigned short* Vtb = Vt + ((size_t)b * DD + h * DHH) * SS;
  const float gneg = -fabsf(gam[h]);

  const int srow = tid >> 3;
  const int sdb = (tid & 7) * 8;

  // Q fragments: loop-invariant, direct global -> registers
  const unsigned short* qrow = Qb + (size_t)(i0 + wr * 16 + fr) * DD;
  short8 a0 = *(const short8*)(qrow + fq * 8);
  short8 a1 = *(const short8*)(qrow + 32 + fq * 8);

  short8 kreg = *(const short8*)(Qb + (size_t)srow * DD + sdb);
  for (int jt = 0; jt < njt; ++jt) {
    *(short8*)&KV[srow][sdb] = kreg;
    const unsigned short* nsrc = (jt + 1 < njt)
        ? Qb + (size_t)((jt + 1) * 64 + srow) * DD + sdb
        : Vtb + (size_t)srow * SS + sdb;
    kreg = *(const short8*)nsrc;
    __syncthreads();

    short8 b0 = *(const short8*)&KV[wc * 16 + fr][fq * 8];
    short8 b1 = *(const short8*)&KV[wc * 16 + fr][32 + fq * 8];
    f32x4 s0 = {};
    __builtin_amdgcn_s_setprio(1);
    s0 = __builtin_amdgcn_mfma_f32_16x16x32_bf16(a0, b0, s0, 0, 0, 0);
    s0 = __builtin_amdgcn_mfma_f32_16x16x32_bf16(a1, b1, s0, 0, 0, 0);
    __builtin_amdgcn_s_setprio(0);

    const int j = jt * 64 + wc * 16 + fr;
#pragma unroll
    for (int r = 0; r < 4; ++r) {
      const int row = wr * 16 + fq * 4 + r;
      sc_s[row][j] = (j < i0 + row) ? s0[r] * 0.125f : -1e30f;
    }
    __syncthreads();
  }
  *(short8*)&KV[srow][sdb] = kreg;   // V tile 0

  if (itile >= 8) {
    // ---- full-wave softmax, 4 passes ----
    const int jb = lane << 3;
#pragma unroll 2
    for (int q = 0; q < 4; ++q) {
      const int r_i = w * 4 + q;
      const int gi = i0 + r_i;
      const float* rowp = &sc_s[r_i][0];
      float4 v0 = *(const float4*)(rowp + jb);
      float4 v1 = *(const float4*)(rowp + jb + 4);
      float sc[8] = {v0.x, v0.y, v0.z, v0.w, v1.x, v1.y, v1.z, v1.w};
#pragma unroll
      for (int c = 0; c < 8; ++c)
        if (jb + c >= jcap) sc[c] = -1e30f;

      // softmax#1: max-free (ratio-invariant)
      float p[8];
      float lsum = 0.0f;
#pragma unroll
      for (int c = 0; c < 8; ++c) {
        p[c] = __expf(sc[c]);
        lsum += p[c];
      }

      float xs = lsum;
#pragma unroll
      for (int off = 1; off < 64; off <<= 1) {
        float y = __shfl_up(xs, off);
        if (lane >= off) xs += y;
      }
      const float tot = __shfl(xs, 63);
      const float inv = 1.0f / tot;
      float run = xs - lsum;

      float s2[8];
#pragma unroll
      for (int c = 0; c < 8; ++c) {
        run += p[c];
        float cum = run * inv;
        float dist = sqrtf(fmaxf((1.0f - cum) * (float)(gi - (jb + c)), 0.0f));
        float te = __expf(gneg * dist);
        te = fminf(fmaxf(te, 1e-5f), 1e5f);
        s2[c] = sc[c] * te;
      }

      // softmax#2: max REQUIRED (maxout scale relies on max(e)==1)
      float m2 = s2[0];
#pragma unroll
      for (int c = 1; c < 8; ++c) m2 = fmaxf(m2, s2[c]);
      m2 = wave_max(m2);
      float e[8];
      float lsum2 = 0.0f;
#pragma unroll
      for (int c = 0; c < 8; ++c) {
        e[c] = __expf(s2[c] - m2);
        lsum2 += e[c];
      }
      float tot2 = wave_sum(lsum2);
      float mult = fminf(tot2, 5.0f) / tot2;

      float av[8];
#pragma unroll
      for (int c = 0; c < 8; ++c) av[c] = (gi == 0) ? 0.0f : e[c] * mult;

      if (scores_out) {
        float* so = scores_out + ((size_t)(b * HH + h) * SS + gi) * SS + jb;
        *(float4*)(so) = make_float4(av[0], av[1], av[2], av[3]);
        *(float4*)(so + 4) = make_float4(av[4], av[5], av[6], av[7]);
      }

      short8 pk;
#pragma unroll
      for (int c = 0; c < 8; ++c) pk[c] = (short)f2bf(av[c]);
      *(short8*)((unsigned short*)&sc_s[r_i][0] + jb) = pk;
    }
  } else {
    // ---- half-wave softmax, 2 passes (jcap <= 256) ----
    const int half = lane >> 5;
    const int ll = lane & 31;
    const int jb = ll << 3;
    for (int q = 0; q < 2; ++q) {
      const int r_i = w * 4 + q * 2 + half;
      const int gi = i0 + r_i;
      const float* rowp = &sc_s[r_i][0];
      float4 v0 = *(const float4*)(rowp + jb);
      float4 v1 = *(const float4*)(rowp + jb + 4);
      float sc[8] = {v0.x, v0.y, v0.z, v0.w, v1.x, v1.y, v1.z, v1.w};
#pragma unroll
      for (int c = 0; c < 8; ++c)
        if (jb + c >= jcap) sc[c] = -1e30f;

      // softmax#1: max-free
      float p[8];
      float lsum = 0.0f;
#pragma unroll
      for (int c = 0; c < 8; ++c) {
        p[c] = __expf(sc[c]);
        lsum += p[c];
      }

      float xs = lsum;
#pragma unroll
      for (int off = 1; off < 32; off <<= 1) {
        float y = __shfl_up(xs, off, 32);
        if (ll >= off) xs += y;
      }
      const float tot = __shfl(xs, 31, 32);
      const float inv = 1.0f / tot;
      float run = xs - lsum;

      float s2[8];
#pragma unroll
      for (int c = 0; c < 8; ++c) {
        run += p[c];
        float cum = run * inv;
        float dist = sqrtf(fmaxf((1.0f - cum) * (float)(gi - (jb + c)), 0.0f));
        float te = __expf(gneg * dist);
        te = fminf(fmaxf(te, 1e-5f), 1e5f);
        s2[c] = sc[c] * te;
      }

      // softmax#2: max required for maxout
      float m2 = s2[0];
#pragma unroll
      for (int c = 1; c < 8; ++c) m2 = fmaxf(m2, s2[c]);
      m2 = half_max(m2);
      float e[8];
      float lsum2 = 0.0f;
#pragma unroll
      for (int c = 0; c < 8; ++c) {
        e[c] = __expf(s2[c] - m2);
        lsum2 += e[c];
      }
      const float tot2 = half_sum(lsum2);
      const float mult = fminf(tot2, 5.0f) / tot2;

      float av[8];
#pragma unroll
      for (int c = 0; c < 8; ++c) av[c] = (gi == 0) ? 0.0f : e[c] * mult;

      if (scores_out) {
        float* so = scores_out + ((size_t)(b * HH + h) * SS + gi) * SS + jb;
        *(float4*)(so) = make_float4(av[0], av[1], av[2], av[3]);
        *(float4*)(so + 4) = make_float4(av[4], av[5], av[6], av[7]);
        *(float4*)(so + 256) = make_float4(0.f, 0.f, 0.f, 0.f);
        *(float4*)(so + 260) = make_float4(0.f, 0.f, 0.f, 0.f);
      }

      short8 pk;
#pragma unroll
      for (int c = 0; c < 8; ++c) pk[c] = (short)f2bf(av[c]);
      *(short8*)((unsigned short*)&sc_s[r_i][0] + jb) = pk;
    }
  }
  __syncthreads();   // attn bf16 + V0 visible

  short8 vreg;
  if (njt > 1) vreg = *(const short8*)(Vtb + (size_t)srow * SS + 64 + sdb);
  f32x4 o0 = {};
  for (int jt = 0; jt < njt; ++jt) {
    const unsigned short* arow = (const unsigned short*)&sc_s[wr * 16 + fr][0];
    short8 pa0 = *(const short8*)(arow + jt * 64 + fq * 8);
    short8 pa1 = *(const short8*)(arow + jt * 64 + 32 + fq * 8);
    short8 c0 = *(const short8*)&KV[wc * 16 + fr][fq * 8];
    short8 c1 = *(const short8*)&KV[wc * 16 + fr][32 + fq * 8];
    __builtin_amdgcn_s_setprio(1);
    o0 = __builtin_amdgcn_mfma_f32_16x16x32_bf16(pa0, c0, o0, 0, 0, 0);
    o0 = __builtin_amdgcn_mfma_f32_16x16x32_bf16(pa1, c1, o0, 0, 0, 0);
    __builtin_amdgcn_s_setprio(0);
    __syncthreads();                       // KV reads done
    if (jt + 1 < njt) {
      *(short8*)&KV[srow][sdb] = vreg;
      if (jt + 2 < njt) vreg = *(const short8*)(Vtb + (size_t)srow * SS + (jt + 2) * 64 + sdb);
      __syncthreads();                     // next V tile visible
    }
  }

  {
    const int d = h * DHH + wc * 16 + fr;
#pragma unroll
    for (int r = 0; r < 4; ++r) {
      const int row = i0 + wr * 16 + fq * 4 + r;
      AO[((size_t)b * SS + row) * DD + d] = f2bf(o0[r]);
    }
  }
}

// ---------------- residual + layernorm, bf16 activations ----------------
// x (bf16 residual) [+ r (bf16 proj)] -> LN -> bf16 outb OR fp32 outf.
__global__ __launch_bounds__(256) void k_res_ln(
    const unsigned short* __restrict__ x, const unsigned short* __restrict__ r,
    const float* __restrict__ w, const float* __restrict__ b,
    unsigned short* __restrict__ outb, float* __restrict__ outf) {
  __shared__ float red[4];
  const int row = blockIdx.x;
  const int tid = threadIdx.x;
  const int lane = tid & 63, wv = tid >> 6;
  uint2 xa = ((const uint2*)(x + (size_t)row * DD))[tid];
  float y0 = bf2f((unsigned short)xa.x);
  float y1 = bf2f((unsigned short)(xa.x >> 16));
  float y2 = bf2f((unsigned short)xa.y);
  float y3 = bf2f((unsigned short)(xa.y >> 16));
  if (r) {
    uint2 ra = ((const uint2*)(r + (size_t)row * DD))[tid];
    y0 += bf2f((unsigned short)ra.x);
    y1 += bf2f((unsigned short)(ra.x >> 16));
    y2 += bf2f((unsigned short)ra.y);
    y3 += bf2f((unsigned short)(ra.y >> 16));
  }
  float s = y0 + y1 + y2 + y3;
  s = wave_sum(s);
  if (lane == 0) red[wv] = s;
  __syncthreads();
  float mean = (red[0] + red[1] + red[2] + red[3]) * (1.0f / DD);
  __syncthreads();
  float d0 = y0 - mean, d1 = y1 - mean, d2 = y2 - mean, d3 = y3 - mean;
  float s2 = d0 * d0 + d1 * d1 + d2 * d2 + d3 * d3;
  s2 = wave_sum(s2);
  if (lane == 0) red[wv] = s2;
  __syncthreads();
  float var = (red[0] + red[1] + red[2] + red[3]) * (1.0f / DD);
  float rstd = rsqrtf(var + 1e-5f);
  float4 ww = ((const float4*)w)[tid];
  float4 bb = ((const float4*)b)[tid];
  float o0 = d0 * rstd * ww.x + bb.x;
  float o1 = d1 * rstd * ww.y + bb.y;
  float o2 = d2 * rstd * ww.z + bb.z;
  float o3 = d3 * rstd * ww.w + bb.w;
  if (outf) {
    ((float4*)(outf + (size_t)row * DD))[tid] = make_float4(o0, o1, o2, o3);
  } else {
    uint2 pk;
    pk.x = (unsigned)f2bf(o0) | ((unsigned)f2bf(o1) << 16);
    pk.y = (unsigned)f2bf(o2) | ((unsigned)f2bf(o3) << 16);
    ((uint2*)(outb + (size_t)row * DD))[tid] = pk;
  }
}

extern "C" void kernel_launch(void* const* d_in, const int* in_sizes, int n_in,
                              void* d_out, int out_size, void* d_ws, size_t ws_size,
                              hipStream_t stream) {
  (void)in_sizes; (void)n_in; (void)out_size; (void)ws_size;
  const float* x = (const float*)d_in[0];
  const float* Wq = (const float*)d_in[2];
  const float* bq = (const float*)d_in[3];
  const float* Wv = (const float*)d_in[4];
  const float* bv = (const float*)d_in[5];
  const float* Wo = (const float*)d_in[6];
  const float* bo = (const float*)d_in[7];
  const float* gam = (const float*)d_in[8];
  const float* lnw = (const float*)d_in[9];
  const float* lnb = (const float*)d_in[10];
  const float* flnw = (const float*)d_in[11];
  const float* flnb = (const float*)d_in[12];

  float* out0 = (float*)d_out;
  float* scores = out0 + (size_t)BB * SS * DD;
  const size_t BUF = (size_t)BB * SS * DD;
  const size_t WSZ = (size_t)LL * DD * DD;
  const size_t BHSS = (size_t)BB * HH * SS * SS;

  unsigned short* us = (unsigned short*)d_ws;
  unsigned short* Abf0 = us;
  unsigned short* Abf1 = us + BUF;
  unsigned short* Qbf = us + 2 * BUF;
  unsigned short* VtB = us + 3 * BUF;
  unsigned short* AObf = us + 4 * BUF;
  unsigned short* Pb = us + 5 * BUF;
  unsigned short* Wob = us + 6 * BUF;
  unsigned short* Wqvb = (unsigned short*)scores + (2 * BHSS - 2 * WSZ);

  const int M = BB * SS;

  k_w2bf_all<<<dim3(3 * WSZ / 1024), 256, 0, stream>>>(Wq, Wv, Wo, Wqvb, Wob);
  k_add_pe<<<dim3(BUF / 1024), 256, 0, stream>>>(x, Abf0);

  unsigned short* Acur = Abf0;
  unsigned short* Anx = Abf1;
  for (int l = 0; l < LL; ++l) {
    float* sc_dst = (l == LL - 1) ? scores : nullptr;
    k_gemm<3><<<dim3(1024), 256, 0, stream>>>(Acur, Wqvb + (size_t)l * 2048 * DD,
                                              bq + l * DD, bv + l * DD, Qbf, VtB);
    k_attn<<<dim3(BB * HH * 16), 512, 0, stream>>>(Qbf, VtB, gam + l * HH, AObf, sc_dst);
    k_gemm<0><<<dim3(512), 256, 0, stream>>>(AObf, Wob + (size_t)l * DD * DD,
                                             bo + l * DD, nullptr, Pb, nullptr);
    k_res_ln<<<dim3(M), 256, 0, stream>>>(Acur, Pb, lnw + l * DD, lnb + l * DD, Anx, nullptr);
    unsigned short* t = Acur; Acur = Anx; Anx = t;
  }
  k_res_ln<<<dim3(M), 256, 0, stream>>>(Acur, nullptr, flnw, flnb, nullptr, out0);
}

// Round 15
// 786.690 us; speedup vs baseline: 1.2719x; 1.0434x over previous
//
#include <hip/hip_runtime.h>
#include <hip/hip_bf16.h>

#define BB 16
#define SS 512
#define DD 1024
#define HH 16
#define LL 4
#define DHH 64
#define GK 1024

typedef __attribute__((ext_vector_type(8))) short short8;
typedef __attribute__((ext_vector_type(4))) float f32x4;
typedef __attribute__((ext_vector_type(8))) _Float16 half8;

__device__ __forceinline__ unsigned short f2bf(float f) {
  union { float f; unsigned int u; } v; v.f = f;
  unsigned int r = v.u + 0x7FFFu + ((v.u >> 16) & 1u);
  return (unsigned short)(r >> 16);
}
__device__ __forceinline__ float bf2f(unsigned short u) {
  union { unsigned int i; float f; } v; v.i = ((unsigned)u) << 16; return v.f;
}

__device__ __forceinline__ float wave_max(float v) {
#pragma unroll
  for (int off = 32; off > 0; off >>= 1) v = fmaxf(v, __shfl_xor(v, off));
  return v;
}
__device__ __forceinline__ float wave_sum(float v) {
#pragma unroll
  for (int off = 32; off > 0; off >>= 1) v += __shfl_xor(v, off);
  return v;
}
__device__ __forceinline__ float half_max(float v) {   // width-32 segment
#pragma unroll
  for (int off = 16; off > 0; off >>= 1) v = fmaxf(v, __shfl_xor(v, off));
  return v;
}
__device__ __forceinline__ float half_sum(float v) {
#pragma unroll
  for (int off = 16; off > 0; off >>= 1) v += __shfl_xor(v, off);
  return v;
}

// global -> LDS direct 16B copy. LDS dest is wave-uniform base + lane*16.
__device__ __forceinline__ void gl16(const void* g, void* l) {
  __builtin_amdgcn_global_load_lds(
      (const __attribute__((address_space(1))) unsigned int*)(uintptr_t)g,
      (__attribute__((address_space(3))) unsigned int*)(unsigned int)(uintptr_t)l,
      16, 0, 0);
}

// ---------------- all weights fp32 -> bf16 in ONE launch ----------------
__global__ __launch_bounds__(256) void k_w2bf_all(
    const float* __restrict__ wq, const float* __restrict__ wv,
    const float* __restrict__ wo, unsigned short* __restrict__ oqv,
    unsigned short* __restrict__ oo) {
  size_t i4 = ((size_t)blockIdx.x * 256 + threadIdx.x) * 4;
  const size_t QV = (size_t)2 * LL * DD * DD;
  const float* src;
  unsigned short* dst;
  if (i4 < QV) {
    size_t l = i4 >> 21;
    size_t r = i4 & ((1u << 21) - 1);
    src = (r < (1u << 20)) ? wq + (l << 20) + r
                           : wv + (l << 20) + (r - (1u << 20));
    dst = oqv + i4;
  } else {
    size_t j = i4 - QV;
    src = wo + j;
    dst = oo + j;
  }
  float4 v = *(const float4*)src;
  uint2 pk;
  pk.x = (unsigned)f2bf(v.x) | ((unsigned)f2bf(v.y) << 16);
  pk.y = (unsigned)f2bf(v.z) | ((unsigned)f2bf(v.w) << 16);
  *(uint2*)dst = pk;
}

// ---------------- q0 = bf16(x + positional encoding) ----------------
__global__ __launch_bounds__(256) void k_add_pe(const float* __restrict__ x,
                                                unsigned short* __restrict__ outb) {
  size_t i4 = ((size_t)blockIdx.x * 256 + threadIdx.x) * 4;
  int d0 = (int)(i4 & (DD - 1));
  int s = (int)((i4 >> 10) & (SS - 1));
  float4 xv = *(const float4*)(x + i4);
  int ip0 = d0 >> 1;
  float f0 = __expf((float)ip0 * -0.017988946039016f);
  float f1 = __expf((float)(ip0 + 1) * -0.017988946039016f);
  float s0v, c0v, s1v, c1v;
  __sincosf((float)s * f0, &s0v, &c0v);
  __sincosf((float)s * f1, &s1v, &c1v);
  float o0 = xv.x + s0v, o1 = xv.y + c0v, o2 = xv.z + s1v, o3 = xv.w + c1v;
  uint2 pk;
  pk.x = (unsigned)f2bf(o0) | ((unsigned)f2bf(o1) << 16);
  pk.y = (unsigned)f2bf(o2) | ((unsigned)f2bf(o3) << 16);
  *(uint2*)(outb + i4) = pk;
}

// ---------------- C = A[M,K]bf16 @ W[N,K]^T bf16 + bias ----------------
// MODE 0: bf16 [M,1024].
// MODE 3: fused QV (N=2048): col<1024 -> bf16 Qbf; col>=1024 -> transposed VtB.
template <int MODE>
__global__ __launch_bounds__(256) void k_gemm(
    const unsigned short* __restrict__ A, const unsigned short* __restrict__ W,
    const float* __restrict__ bias, const float* __restrict__ bias2,
    void* __restrict__ out, void* __restrict__ out2) {
  __shared__ unsigned short As[2][128 * 32];
  __shared__ unsigned short Bs[2][128 * 32];
  const int tid = threadIdx.x;
  const int lane = tid & 63;
  const int w = tid >> 6;
  const int wr = w >> 1, wc = w & 1;
  const int fr = lane & 15, fq = lane >> 4;

  int bid = blockIdx.x;
  const int cpx = gridDim.x >> 3;
  bid = (bid & 7) * cpx + (bid >> 3);
  const int bm = (bid & 63) * 128;
  const int bn = (bid >> 6) * 128;

  f32x4 acc[4][4] = {};

  const unsigned short* ga = A + (size_t)(bm + w * 16 + (lane >> 2)) * GK + (lane & 3) * 8;
  const unsigned short* gb = W + (size_t)(bn + w * 16 + (lane >> 2)) * GK + (lane & 3) * 8;

  auto STAGE = [&](int buf, int k0) {
    unsigned short* la = As[buf] + w * 512;
    unsigned short* lb = Bs[buf] + w * 512;
    gl16(ga + k0, la);
    gl16(ga + 64 * GK + k0, la + 2048);
    gl16(gb + k0, lb);
    gl16(gb + 64 * GK + k0, lb + 2048);
  };

  STAGE(0, 0);
  __syncthreads();
  int cur = 0;
  for (int k0 = 0; k0 < GK; k0 += 32) {
    if (k0 + 32 < GK) STAGE(cur ^ 1, k0 + 32);
    short8 af[4], bf[4];
#pragma unroll
    for (int m = 0; m < 4; ++m)
      af[m] = *(const short8*)(As[cur] + (wr * 64 + m * 16 + fr) * 32 + fq * 8);
#pragma unroll
    for (int n = 0; n < 4; ++n)
      bf[n] = *(const short8*)(Bs[cur] + (wc * 64 + n * 16 + fr) * 32 + fq * 8);
#pragma unroll
    for (int m = 0; m < 4; ++m)
#pragma unroll
      for (int n = 0; n < 4; ++n)
        acc[m][n] = __builtin_amdgcn_mfma_f32_16x16x32_bf16(af[m], bf[n], acc[m][n], 0, 0, 0);
    __syncthreads();
    cur ^= 1;
  }

#pragma unroll
  for (int m = 0; m < 4; ++m) {
    const int row0 = bm + wr * 64 + m * 16 + fq * 4;
#pragma unroll
    for (int n = 0; n < 4; ++n) {
      const int col = bn + wc * 64 + n * 16 + fr;
      if constexpr (MODE == 0) {
        const float bsv = bias[col];
        unsigned short* o = (unsigned short*)out;
#pragma unroll
        for (int r = 0; r < 4; ++r)
          o[(size_t)(row0 + r) * DD + col] = f2bf(acc[m][n][r] + bsv);
      } else {  // MODE 3: fused QV
        if (col < DD) {
          const float bsv = bias[col];
          unsigned short* o = (unsigned short*)out;
#pragma unroll
          for (int r = 0; r < 4; ++r)
            o[(size_t)(row0 + r) * DD + col] = f2bf(acc[m][n][r] + bsv);
        } else {
          const int c2 = col - DD;
          const float bsv = bias2[c2];
          unsigned short* o = (unsigned short*)out2;
          const int bi = row0 >> 9, si = row0 & (SS - 1);
          uint2 pk;
          pk.x = (unsigned)f2bf(acc[m][n][0] + bsv) | ((unsigned)f2bf(acc[m][n][1] + bsv) << 16);
          pk.y = (unsigned)f2bf(acc[m][n][2] + bsv) | ((unsigned)f2bf(acc[m][n][3] + bsv) << 16);
          *(uint2*)(o + ((size_t)bi * DD + c2) * SS + si) = pk;
        }
      }
    }
  }
}

// ---------------- fused MFMA attention: 64-row i-tiles, fp16 score LDS ----------------
// 2048 blocks (8 itiles x 256 bh), longest itiles first (LPT).
// 8 waves: wr=w&3 (16-row block), wc=w>>2 (32-col block). Scores stored fp16
// (65KB), K/V staged with register prefetch, attn rewritten in place as bf16.
__global__ __launch_bounds__(512) void k_attn(
    const unsigned short* __restrict__ Q, const unsigned short* __restrict__ Vt,
    const float* __restrict__ gam, unsigned short* __restrict__ AO,
    float* __restrict__ scores_out) {
  __shared__ _Float16 sc_s[64][520];       // 66560 B
  __shared__ unsigned short KV[64][72];    //  9216 B => 75776 B, 2 blk/CU

  const int tid = threadIdx.x;
  const int lane = tid & 63;
  const int w = tid >> 6;
  const int wr = w & 3;        // 16-row block
  const int wc = w >> 2;       // 32-col/dim block
  const int fr = lane & 15, fq = lane >> 4;

  const int itile = 7 - (blockIdx.x >> 8);    // 7..0: longest first
  const int bh = blockIdx.x & 255;
  const int b = bh >> 4;
  const int h = bh & 15;
  const int i0 = itile * 64;
  const int njt = itile + 1;                  // 1..8
  const int jcap = njt * 64;

  const unsigned short* Qb = Q + (size_t)b * SS * DD + h * DHH;
  const unsigned short* Vtb = Vt + ((size_t)b * DD + h * DHH) * SS;
  const float gneg = -fabsf(gam[h]);

  const int srow = tid >> 3;
  const int sdb = (tid & 7) * 8;

  // Q fragments: loop-invariant, direct global -> registers
  const unsigned short* qrow = Qb + (size_t)(i0 + wr * 16 + fr) * DD;
  short8 a0 = *(const short8*)(qrow + fq * 8);
  short8 a1 = *(const short8*)(qrow + 32 + fq * 8);

  short8 kreg = *(const short8*)(Qb + (size_t)srow * DD + sdb);
  for (int jt = 0; jt < njt; ++jt) {
    *(short8*)&KV[srow][sdb] = kreg;
    const unsigned short* nsrc = (jt + 1 < njt)
        ? Qb + (size_t)((jt + 1) * 64 + srow) * DD + sdb
        : Vtb + (size_t)srow * SS + sdb;
    kreg = *(const short8*)nsrc;
    __syncthreads();

    short8 b00 = *(const short8*)&KV[wc * 32 + fr][fq * 8];
    short8 b01 = *(const short8*)&KV[wc * 32 + fr][32 + fq * 8];
    short8 b10 = *(const short8*)&KV[wc * 32 + 16 + fr][fq * 8];
    short8 b11 = *(const short8*)&KV[wc * 32 + 16 + fr][32 + fq * 8];
    f32x4 s0 = {}, s1 = {};
    __builtin_amdgcn_s_setprio(1);
    s0 = __builtin_amdgcn_mfma_f32_16x16x32_bf16(a0, b00, s0, 0, 0, 0);
    s0 = __builtin_amdgcn_mfma_f32_16x16x32_bf16(a1, b01, s0, 0, 0, 0);
    s1 = __builtin_amdgcn_mfma_f32_16x16x32_bf16(a0, b10, s1, 0, 0, 0);
    s1 = __builtin_amdgcn_mfma_f32_16x16x32_bf16(a1, b11, s1, 0, 0, 0);
    __builtin_amdgcn_s_setprio(0);

#pragma unroll
    for (int n = 0; n < 2; ++n) {
      const int j = jt * 64 + wc * 32 + n * 16 + fr;
#pragma unroll
      for (int r = 0; r < 4; ++r) {
        const int row = wr * 16 + fq * 4 + r;
        const float val = (n ? s1[r] : s0[r]) * 0.125f;
        sc_s[row][j] = (j < i0 + row) ? (_Float16)val : (_Float16)(-65504.0f);
      }
    }
    __syncthreads();
  }
  *(short8*)&KV[srow][sdb] = kreg;   // V tile 0

  if (itile >= 4) {
    // ---- full-wave softmax, 8 passes ----
    const int jb = lane << 3;
#pragma unroll 2
    for (int q = 0; q < 8; ++q) {
      const int r_i = w * 8 + q;
      const int gi = i0 + r_i;
      half8 hv = *(const half8*)(&sc_s[r_i][0] + jb);
      float sc[8];
#pragma unroll
      for (int c = 0; c < 8; ++c) sc[c] = (float)hv[c];
#pragma unroll
      for (int c = 0; c < 8; ++c)
        if (jb + c >= jcap) sc[c] = -1e30f;

      // softmax#1: max-free (ratio-invariant)
      float p[8];
      float lsum = 0.0f;
#pragma unroll
      for (int c = 0; c < 8; ++c) {
        p[c] = __expf(sc[c]);
        lsum += p[c];
      }

      float xs = lsum;
#pragma unroll
      for (int off = 1; off < 64; off <<= 1) {
        float y = __shfl_up(xs, off);
        if (lane >= off) xs += y;
      }
      const float tot = __shfl(xs, 63);
      const float inv = 1.0f / tot;
      float run = xs - lsum;

      float s2[8];
#pragma unroll
      for (int c = 0; c < 8; ++c) {
        run += p[c];
        float cum = run * inv;
        float dist = sqrtf(fmaxf((1.0f - cum) * (float)(gi - (jb + c)), 0.0f));
        float te = __expf(gneg * dist);
        te = fminf(fmaxf(te, 1e-5f), 1e5f);
        s2[c] = sc[c] * te;
      }

      // softmax#2: max REQUIRED (maxout scale relies on max(e)==1)
      float m2 = s2[0];
#pragma unroll
      for (int c = 1; c < 8; ++c) m2 = fmaxf(m2, s2[c]);
      m2 = wave_max(m2);
      float e[8];
      float lsum2 = 0.0f;
#pragma unroll
      for (int c = 0; c < 8; ++c) {
        e[c] = __expf(s2[c] - m2);
        lsum2 += e[c];
      }
      float tot2 = wave_sum(lsum2);
      float mult = fminf(tot2, 5.0f) / tot2;

      float av[8];
#pragma unroll
      for (int c = 0; c < 8; ++c) av[c] = (gi == 0) ? 0.0f : e[c] * mult;

      if (scores_out) {
        float* so = scores_out + ((size_t)(b * HH + h) * SS + gi) * SS + jb;
        *(float4*)(so) = make_float4(av[0], av[1], av[2], av[3]);
        *(float4*)(so + 4) = make_float4(av[4], av[5], av[6], av[7]);
      }

      short8 pk;
#pragma unroll
      for (int c = 0; c < 8; ++c) pk[c] = (short)f2bf(av[c]);
      *(short8*)((unsigned short*)&sc_s[r_i][0] + jb) = pk;
    }
  } else {
    // ---- half-wave softmax, 4 passes (jcap <= 256) ----
    const int half = lane >> 5;
    const int ll = lane & 31;
    const int jb = ll << 3;
    for (int q = 0; q < 4; ++q) {
      const int r_i = w * 8 + q * 2 + half;
      const int gi = i0 + r_i;
      half8 hv = *(const half8*)(&sc_s[r_i][0] + jb);
      float sc[8];
#pragma unroll
      for (int c = 0; c < 8; ++c) sc[c] = (float)hv[c];
#pragma unroll
      for (int c = 0; c < 8; ++c)
        if (jb + c >= jcap) sc[c] = -1e30f;

      // softmax#1: max-free
      float p[8];
      float lsum = 0.0f;
#pragma unroll
      for (int c = 0; c < 8; ++c) {
        p[c] = __expf(sc[c]);
        lsum += p[c];
      }

      float xs = lsum;
#pragma unroll
      for (int off = 1; off < 32; off <<= 1) {
        float y = __shfl_up(xs, off, 32);
        if (ll >= off) xs += y;
      }
      const float tot = __shfl(xs, 31, 32);
      const float inv = 1.0f / tot;
      float run = xs - lsum;

      float s2[8];
#pragma unroll
      for (int c = 0; c < 8; ++c) {
        run += p[c];
        float cum = run * inv;
        float dist = sqrtf(fmaxf((1.0f - cum) * (float)(gi - (jb + c)), 0.0f));
        float te = __expf(gneg * dist);
        te = fminf(fmaxf(te, 1e-5f), 1e5f);
        s2[c] = sc[c] * te;
      }

      // softmax#2: max required for maxout
      float m2 = s2[0];
#pragma unroll
      for (int c = 1; c < 8; ++c) m2 = fmaxf(m2, s2[c]);
      m2 = half_max(m2);
      float e[8];
      float lsum2 = 0.0f;
#pragma unroll
      for (int c = 0; c < 8; ++c) {
        e[c] = __expf(s2[c] - m2);
        lsum2 += e[c];
      }
      const float tot2 = half_sum(lsum2);
      const float mult = fminf(tot2, 5.0f) / tot2;

      float av[8];
#pragma unroll
      for (int c = 0; c < 8; ++c) av[c] = (gi == 0) ? 0.0f : e[c] * mult;

      if (scores_out) {
        float* so = scores_out + ((size_t)(b * HH + h) * SS + gi) * SS + jb;
        *(float4*)(so) = make_float4(av[0], av[1], av[2], av[3]);
        *(float4*)(so + 4) = make_float4(av[4], av[5], av[6], av[7]);
        *(float4*)(so + 256) = make_float4(0.f, 0.f, 0.f, 0.f);
        *(float4*)(so + 260) = make_float4(0.f, 0.f, 0.f, 0.f);
      }

      short8 pk;
#pragma unroll
      for (int c = 0; c < 8; ++c) pk[c] = (short)f2bf(av[c]);
      *(short8*)((unsigned short*)&sc_s[r_i][0] + jb) = pk;
    }
  }
  __syncthreads();   // attn bf16 + V0 visible

  short8 vreg;
  if (njt > 1) vreg = *(const short8*)(Vtb + (size_t)srow * SS + 64 + sdb);
  f32x4 o0 = {}, o1 = {};
  for (int jt = 0; jt < njt; ++jt) {
    const unsigned short* arow = (const unsigned short*)&sc_s[wr * 16 + fr][0];
    short8 pa0 = *(const short8*)(arow + jt * 64 + fq * 8);
    short8 pa1 = *(const short8*)(arow + jt * 64 + 32 + fq * 8);
    short8 c00 = *(const short8*)&KV[wc * 32 + fr][fq * 8];
    short8 c01 = *(const short8*)&KV[wc * 32 + fr][32 + fq * 8];
    short8 c10 = *(const short8*)&KV[wc * 32 + 16 + fr][fq * 8];
    short8 c11 = *(const short8*)&KV[wc * 32 + 16 + fr][32 + fq * 8];
    __builtin_amdgcn_s_setprio(1);
    o0 = __builtin_amdgcn_mfma_f32_16x16x32_bf16(pa0, c00, o0, 0, 0, 0);
    o0 = __builtin_amdgcn_mfma_f32_16x16x32_bf16(pa1, c01, o0, 0, 0, 0);
    o1 = __builtin_amdgcn_mfma_f32_16x16x32_bf16(pa0, c10, o1, 0, 0, 0);
    o1 = __builtin_amdgcn_mfma_f32_16x16x32_bf16(pa1, c11, o1, 0, 0, 0);
    __builtin_amdgcn_s_setprio(0);
    __syncthreads();                       // KV reads done
    if (jt + 1 < njt) {
      *(short8*)&KV[srow][sdb] = vreg;
      if (jt + 2 < njt) vreg = *(const short8*)(Vtb + (size_t)srow * SS + (jt + 2) * 64 + sdb);
      __syncthreads();                     // next V tile visible
    }
  }

#pragma unroll
  for (int n = 0; n < 2; ++n) {
    const int d = h * DHH + wc * 32 + n * 16 + fr;
#pragma unroll
    for (int r = 0; r < 4; ++r) {
      const int row = i0 + wr * 16 + fq * 4 + r;
      AO[((size_t)b * SS + row) * DD + d] = f2bf(n ? o1[r] : o0[r]);
    }
  }
}

// ---------------- residual + layernorm, bf16 activations ----------------
__global__ __launch_bounds__(256) void k_res_ln(
    const unsigned short* __restrict__ x, const unsigned short* __restrict__ r,
    const float* __restrict__ w, const float* __restrict__ b,
    unsigned short* __restrict__ outb, float* __restrict__ outf) {
  __shared__ float red[4];
  const int row = blockIdx.x;
  const int tid = threadIdx.x;
  const int lane = tid & 63, wv = tid >> 6;
  uint2 xa = ((const uint2*)(x + (size_t)row * DD))[tid];
  float y0 = bf2f((unsigned short)xa.x);
  float y1 = bf2f((unsigned short)(xa.x >> 16));
  float y2 = bf2f((unsigned short)xa.y);
  float y3 = bf2f((unsigned short)(xa.y >> 16));
  if (r) {
    uint2 ra = ((const uint2*)(r + (size_t)row * DD))[tid];
    y0 += bf2f((unsigned short)ra.x);
    y1 += bf2f((unsigned short)(ra.x >> 16));
    y2 += bf2f((unsigned short)ra.y);
    y3 += bf2f((unsigned short)(ra.y >> 16));
  }
  float s = y0 + y1 + y2 + y3;
  s = wave_sum(s);
  if (lane == 0) red[wv] = s;
  __syncthreads();
  float mean = (red[0] + red[1] + red[2] + red[3]) * (1.0f / DD);
  __syncthreads();
  float d0 = y0 - mean, d1 = y1 - mean, d2 = y2 - mean, d3 = y3 - mean;
  float s2 = d0 * d0 + d1 * d1 + d2 * d2 + d3 * d3;
  s2 = wave_sum(s2);
  if (lane == 0) red[wv] = s2;
  __syncthreads();
  float var = (red[0] + red[1] + red[2] + red[3]) * (1.0f / DD);
  float rstd = rsqrtf(var + 1e-5f);
  float4 ww = ((const float4*)w)[tid];
  float4 bb = ((const float4*)b)[tid];
  float o0 = d0 * rstd * ww.x + bb.x;
  float o1 = d1 * rstd * ww.y + bb.y;
  float o2 = d2 * rstd * ww.z + bb.z;
  float o3 = d3 * rstd * ww.w + bb.w;
  if (outf) {
    ((float4*)(outf + (size_t)row * DD))[tid] = make_float4(o0, o1, o2, o3);
  } else {
    uint2 pk;
    pk.x = (unsigned)f2bf(o0) | ((unsigned)f2bf(o1) << 16);
    pk.y = (unsigned)f2bf(o2) | ((unsigned)f2bf(o3) << 16);
    ((uint2*)(outb + (size_t)row * DD))[tid] = pk;
  }
}

extern "C" void kernel_launch(void* const* d_in, const int* in_sizes, int n_in,
                              void* d_out, int out_size, void* d_ws, size_t ws_size,
                              hipStream_t stream) {
  (void)in_sizes; (void)n_in; (void)out_size; (void)ws_size;
  const float* x = (const float*)d_in[0];
  const float* Wq = (const float*)d_in[2];
  const float* bq = (const float*)d_in[3];
  const float* Wv = (const float*)d_in[4];
  const float* bv = (const float*)d_in[5];
  const float* Wo = (const float*)d_in[6];
  const float* bo = (const float*)d_in[7];
  const float* gam = (const float*)d_in[8];
  const float* lnw = (const float*)d_in[9];
  const float* lnb = (const float*)d_in[10];
  const float* flnw = (const float*)d_in[11];
  const float* flnb = (const float*)d_in[12];

  float* out0 = (float*)d_out;
  float* scores = out0 + (size_t)BB * SS * DD;
  const size_t BUF = (size_t)BB * SS * DD;
  const size_t WSZ = (size_t)LL * DD * DD;
  const size_t BHSS = (size_t)BB * HH * SS * SS;

  unsigned short* us = (unsigned short*)d_ws;
  unsigned short* Abf0 = us;
  unsigned short* Abf1 = us + BUF;
  unsigned short* Qbf = us + 2 * BUF;
  unsigned short* VtB = us + 3 * BUF;
  unsigned short* AObf = us + 4 * BUF;
  unsigned short* Pb = us + 5 * BUF;
  unsigned short* Wob = us + 6 * BUF;
  unsigned short* Wqvb = (unsigned short*)scores + (2 * BHSS - 2 * WSZ);

  const int M = BB * SS;

  k_w2bf_all<<<dim3(3 * WSZ / 1024), 256, 0, stream>>>(Wq, Wv, Wo, Wqvb, Wob);
  k_add_pe<<<dim3(BUF / 1024), 256, 0, stream>>>(x, Abf0);

  unsigned short* Acur = Abf0;
  unsigned short* Anx = Abf1;
  for (int l = 0; l < LL; ++l) {
    float* sc_dst = (l == LL - 1) ? scores : nullptr;
    k_gemm<3><<<dim3(1024), 256, 0, stream>>>(Acur, Wqvb + (size_t)l * 2048 * DD,
                                              bq + l * DD, bv + l * DD, Qbf, VtB);
    k_attn<<<dim3(BB * HH * 8), 512, 0, stream>>>(Qbf, VtB, gam + l * HH, AObf, sc_dst);
    k_gemm<0><<<dim3(512), 256, 0, stream>>>(AObf, Wob + (size_t)l * DD * DD,
                                             bo + l * DD, nullptr, Pb, nullptr);
    k_res_ln<<<dim3(M), 256, 0, stream>>>(Acur, Pb, lnw + l * DD, lnb + l * DD, Anx, nullptr);
    unsigned short* t = Acur; Acur = Anx; Anx = t;
  }
  k_res_ln<<<dim3(M), 256, 0, stream>>>(Acur, nullptr, flnw, flnb, nullptr, out0);
}